// Round 1
// baseline (5091.557 us; speedup 1.0000x reference)
//
#include <hip/hip_runtime.h>

// GCN: 3x (scale -> gather -> scatter-add -> GEMM(+bias,+relu))
// Layer3 reordered: z=(norm_src.*x2)@W3 BEFORE aggregation (64 feats not 1024).
constexpr int NN   = 10000;
constexpr int NE   = 160000;
constexpr int F    = 1024;
constexpr int C3   = 64;
constexpr int MPAD = 10112;   // 79 * 128, GEMM M-tile padding (padded rows are benign garbage)

__global__ __launch_bounds__(256) void k_degree(const int* __restrict__ src,
                                                const int* __restrict__ dst,
                                                float* __restrict__ deg_out,
                                                float* __restrict__ deg_in) {
    int e = blockIdx.x * 256 + threadIdx.x;
    if (e < NE) {
        atomicAdd(&deg_out[src[e]], 1.0f);
        atomicAdd(&deg_in[dst[e]], 1.0f);
    }
}

__global__ __launch_bounds__(256) void k_norm(const float* __restrict__ deg_out,
                                              const float* __restrict__ deg_in,
                                              float* __restrict__ norm_src,
                                              float* __restrict__ norm_dst) {
    int v = blockIdx.x * 256 + threadIdx.x;
    if (v < MPAD) {
        norm_src[v] = rsqrtf(fmaxf(deg_out[v], 1.0f));
        norm_dst[v] = rsqrtf(fmaxf(deg_in[v], 1.0f));
    }
}

// one 256-thread block per edge; 1024 feats, float4 per thread
__global__ __launch_bounds__(256) void k_scatter1024(const float* __restrict__ x,
                                                     const int* __restrict__ src,
                                                     const int* __restrict__ dst,
                                                     const float* __restrict__ norm_src,
                                                     float* __restrict__ agg) {
    int e = blockIdx.x;
    int s = src[e], d = dst[e];
    float ns = norm_src[s];
    const float4 v = ((const float4*)(x + (size_t)s * F))[threadIdx.x];
    float* ar = agg + (size_t)d * F + threadIdx.x * 4;
    atomicAdd(ar + 0, v.x * ns);
    atomicAdd(ar + 1, v.y * ns);
    atomicAdd(ar + 2, v.z * ns);
    atomicAdd(ar + 3, v.w * ns);
}

// 16 threads per edge, 64 feats (z already norm_src-scaled via GEMM rowscale)
__global__ __launch_bounds__(256) void k_scatter64(const float* __restrict__ z,
                                                   const int* __restrict__ src,
                                                   const int* __restrict__ dst,
                                                   float* __restrict__ agg) {
    int idx = blockIdx.x * 256 + threadIdx.x;
    int e = idx >> 4;
    if (e >= NE) return;
    int f4 = (idx & 15) * 4;
    int s = src[e], d = dst[e];
    const float4 v = *(const float4*)(z + (size_t)s * C3 + f4);
    float* ar = agg + (size_t)d * C3 + f4;
    atomicAdd(ar + 0, v.x);
    atomicAdd(ar + 1, v.y);
    atomicAdd(ar + 2, v.z);
    atomicAdd(ar + 3, v.w);
}

__global__ __launch_bounds__(256) void k_finalize(const float* __restrict__ agg,
                                                  const float* __restrict__ norm_dst,
                                                  const float* __restrict__ b3,
                                                  float* __restrict__ out) {
    int idx = blockIdx.x * 256 + threadIdx.x;
    if (idx >= NN * C3) return;
    int v = idx >> 6, f = idx & 63;
    out[idx] = agg[(size_t)v * C3 + f] * norm_dst[v] + b3[f];
}

// C[m, n0..] = opt_relu( rowscale[m] * (A @ W)[m,n] + bias[n] )
// A: MPAD x 1024 row-major. W: 1024 x N row-major. Tile: BM=128, BN=64, BK=16,
// 256 threads, 8x4 micro-tile per thread.
__global__ __launch_bounds__(256) void k_gemm(const float* __restrict__ A,
                                              const float* __restrict__ W,
                                              const float* __restrict__ bias,
                                              const float* __restrict__ rowscale,
                                              float* __restrict__ C,
                                              int N, int relu) {
    __shared__ float As[16][128];   // [k][m] transposed
    __shared__ float Bs[16][64];    // [k][n]
    const int t  = threadIdx.x;
    const int tx = t & 15, ty = t >> 4;
    const int m0 = blockIdx.x * 128;
    const int n0 = blockIdx.y * 64;

    const int lar = t >> 1;         // 0..127  A-tile row
    const int lac = (t & 1) * 8;    // 0 or 8  A-tile col (k)
    const int lbr = t >> 4;         // 0..15   W-tile row (k)
    const int lbc = (t & 15) * 4;   // 0..60   W-tile col

    const float* Ap = A + (size_t)(m0 + lar) * F + lac;
    const float* Wp = W + (size_t)lbr * N + n0 + lbc;

    float acc[8][4];
#pragma unroll
    for (int i = 0; i < 8; ++i)
#pragma unroll
        for (int j = 0; j < 4; ++j) acc[i][j] = 0.f;

    for (int kt = 0; kt < F; kt += 16) {
        float4 a0 = *(const float4*)(Ap + kt);
        float4 a1 = *(const float4*)(Ap + kt + 4);
        float4 wv = *(const float4*)(Wp + (size_t)kt * N);
        __syncthreads();
        As[lac + 0][lar] = a0.x; As[lac + 1][lar] = a0.y;
        As[lac + 2][lar] = a0.z; As[lac + 3][lar] = a0.w;
        As[lac + 4][lar] = a1.x; As[lac + 5][lar] = a1.y;
        As[lac + 6][lar] = a1.z; As[lac + 7][lar] = a1.w;
        *(float4*)&Bs[lbr][lbc] = wv;
        __syncthreads();
#pragma unroll
        for (int k = 0; k < 16; ++k) {
            float a[8], b[4];
#pragma unroll
            for (int i = 0; i < 8; ++i) a[i] = As[k][ty * 8 + i];
#pragma unroll
            for (int j = 0; j < 4; ++j) b[j] = Bs[k][tx * 4 + j];
#pragma unroll
            for (int i = 0; i < 8; ++i)
#pragma unroll
                for (int j = 0; j < 4; ++j)
                    acc[i][j] = fmaf(a[i], b[j], acc[i][j]);
        }
    }

    float bv[4];
#pragma unroll
    for (int j = 0; j < 4; ++j) bv[j] = bias ? bias[n0 + tx * 4 + j] : 0.f;
#pragma unroll
    for (int i = 0; i < 8; ++i) {
        int m = m0 + ty * 8 + i;
        float rs = rowscale[m];
        float4 o;
        o.x = acc[i][0] * rs + bv[0];
        o.y = acc[i][1] * rs + bv[1];
        o.z = acc[i][2] * rs + bv[2];
        o.w = acc[i][3] * rs + bv[3];
        if (relu) {
            o.x = fmaxf(o.x, 0.f); o.y = fmaxf(o.y, 0.f);
            o.z = fmaxf(o.z, 0.f); o.w = fmaxf(o.w, 0.f);
        }
        *(float4*)(C + (size_t)m * N + n0 + tx * 4) = o;
    }
}

extern "C" void kernel_launch(void* const* d_in, const int* in_sizes, int n_in,
                              void* d_out, int out_size, void* d_ws, size_t ws_size,
                              hipStream_t stream) {
    const float* h  = (const float*)d_in[0];
    const int*   src = (const int*)d_in[1];
    const int*   dst = (const int*)d_in[2];
    const float* W1 = (const float*)d_in[3];
    const float* b1 = (const float*)d_in[4];
    const float* W2 = (const float*)d_in[5];
    const float* b2 = (const float*)d_in[6];
    const float* W3 = (const float*)d_in[7];
    const float* b3 = (const float*)d_in[8];
    float* out = (float*)d_out;

    float* ws = (float*)d_ws;
    float* deg_out  = ws;                          // MPAD
    float* deg_in   = deg_out + MPAD;              // MPAD
    float* norm_src = deg_in + MPAD;               // MPAD
    float* norm_dst = norm_src + MPAD;             // MPAD
    float* agg      = norm_dst + MPAD;             // MPAD*1024
    float* xbuf     = agg  + (size_t)MPAD * F;     // MPAD*1024
    float* z3       = xbuf + (size_t)MPAD * F;     // MPAD*64
    float* agg3     = z3   + (size_t)MPAD * C3;    // MPAD*64
    // total ~88 MB

    // degrees + norms
    hipMemsetAsync(deg_out, 0, 2 * MPAD * sizeof(float), stream);
    k_degree<<<(NE + 255) / 256, 256, 0, stream>>>(src, dst, deg_out, deg_in);
    k_norm<<<(MPAD + 255) / 256, 256, 0, stream>>>(deg_out, deg_in, norm_src, norm_dst);

    // layer 1: agg = A (norm_src .* h); x1 = relu(norm_dst .* (agg@W1) + b1)
    hipMemsetAsync(agg, 0, (size_t)MPAD * F * sizeof(float), stream);
    k_scatter1024<<<NE, 256, 0, stream>>>(h, src, dst, norm_src, agg);
    k_gemm<<<dim3(MPAD / 128, F / 64), 256, 0, stream>>>(agg, W1, b1, norm_dst, xbuf, F, 1);

    // layer 2
    hipMemsetAsync(agg, 0, (size_t)MPAD * F * sizeof(float), stream);
    k_scatter1024<<<NE, 256, 0, stream>>>(xbuf, src, dst, norm_src, agg);
    k_gemm<<<dim3(MPAD / 128, F / 64), 256, 0, stream>>>(agg, W2, b2, norm_dst, xbuf, F, 1);

    // layer 3 (reordered): z3 = (norm_src .* x2) @ W3 ; agg3 = A z3 ; out = norm_dst .* agg3 + b3
    k_gemm<<<dim3(MPAD / 128, 1), 256, 0, stream>>>(xbuf, W3, nullptr, norm_src, z3, C3, 0);
    hipMemsetAsync(agg3, 0, (size_t)MPAD * C3 * sizeof(float), stream);
    k_scatter64<<<(NE * 16 + 255) / 256, 256, 0, stream>>>(z3, src, dst, agg3);
    k_finalize<<<(NN * C3 + 255) / 256, 256, 0, stream>>>(agg3, norm_dst, b3, out);
}

// Round 2
// 926.484 us; speedup vs baseline: 5.4956x; 5.4956x over previous
//
#include <hip/hip_runtime.h>

// GCN: 3 x (gather-aggregate via CSR -> GEMM(+bias,+relu))
// R1: replaced atomicAdd edge-scatter (2.56 GB HBM write stream, 2x2107us)
//     with CSR-by-dst build + per-node gather aggregation (zero fp32 atomics).
constexpr int NN   = 10000;
constexpr int NE   = 160000;
constexpr int F    = 1024;
constexpr int C3   = 64;
constexpr int MPAD = 10112;   // 79 * 128, GEMM M-tile padding

// ---- CSR build ------------------------------------------------------------

__global__ __launch_bounds__(256) void k_degree(const int* __restrict__ src,
                                                const int* __restrict__ dst,
                                                int* __restrict__ deg_out,
                                                int* __restrict__ deg_in) {
    int e = blockIdx.x * 256 + threadIdx.x;
    if (e < NE) {
        atomicAdd(&deg_out[src[e]], 1);
        atomicAdd(&deg_in[dst[e]], 1);
    }
}

__global__ __launch_bounds__(256) void k_norm(const int* __restrict__ deg_out,
                                              const int* __restrict__ deg_in,
                                              float* __restrict__ norm_src,
                                              float* __restrict__ norm_dst) {
    int v = blockIdx.x * 256 + threadIdx.x;
    if (v < MPAD) {
        norm_src[v] = rsqrtf(fmaxf((float)deg_out[v], 1.0f));
        norm_dst[v] = rsqrtf(fmaxf((float)deg_in[v], 1.0f));
    }
}

// single-block exclusive scan of deg_in[0..NN) -> row_ptr[0..NN], cursor copy
__global__ __launch_bounds__(1024) void k_scan(const int* __restrict__ deg_in,
                                               int* __restrict__ row_ptr,
                                               int* __restrict__ cursor) {
    constexpr int CH = 10;           // 1024 * 10 >= NN
    __shared__ int sums[1024];
    const int tid = threadIdx.x;
    int local[CH];
    int tsum = 0;
#pragma unroll
    for (int j = 0; j < CH; ++j) {
        int idx = tid * CH + j;
        int v = (idx < NN) ? deg_in[idx] : 0;
        local[j] = v;
        tsum += v;
    }
    sums[tid] = tsum;
    __syncthreads();
    // Hillis-Steele inclusive scan over 1024 partials
    for (int off = 1; off < 1024; off <<= 1) {
        int v = (tid >= off) ? sums[tid - off] : 0;
        __syncthreads();
        sums[tid] += v;
        __syncthreads();
    }
    int run = sums[tid] - tsum;      // exclusive prefix of this chunk
#pragma unroll
    for (int j = 0; j < CH; ++j) {
        int idx = tid * CH + j;
        if (idx < NN) {
            row_ptr[idx] = run;
            cursor[idx]  = run;
        }
        run += local[j];
    }
    if (tid == 1023) row_ptr[NN] = sums[1023];
}

__global__ __launch_bounds__(256) void k_bucket(const int* __restrict__ src,
                                                const int* __restrict__ dst,
                                                int* __restrict__ cursor,
                                                int* __restrict__ csr_src) {
    int e = blockIdx.x * 256 + threadIdx.x;
    if (e < NE) {
        int slot = atomicAdd(&cursor[dst[e]], 1);
        csr_src[slot] = src[e];
    }
}

// ---- aggregation (gather) -------------------------------------------------

// one block (256 thr) per dst node; 1024 feats as float4/thread
__global__ __launch_bounds__(256) void k_agg1024(const float* __restrict__ x,
                                                 const int* __restrict__ row_ptr,
                                                 const int* __restrict__ csr_src,
                                                 const float* __restrict__ norm_src,
                                                 float* __restrict__ agg) {
    const int v  = blockIdx.x;
    const int t  = threadIdx.x;
    const int lo = row_ptr[v], hi = row_ptr[v + 1];
    float4 acc = {0.f, 0.f, 0.f, 0.f};
    for (int i = lo; i < hi; ++i) {
        int s = csr_src[i];
        float ns = norm_src[s];
        float4 xv = ((const float4*)(x + (size_t)s * F))[t];
        acc.x = fmaf(ns, xv.x, acc.x);
        acc.y = fmaf(ns, xv.y, acc.y);
        acc.z = fmaf(ns, xv.z, acc.z);
        acc.w = fmaf(ns, xv.w, acc.w);
    }
    ((float4*)(agg + (size_t)v * F))[t] = acc;
}

// 4 nodes per 256-thr block; 64 feats scalar; fused norm_dst & bias epilogue.
// z rows already carry norm_src (GEMM rowscale); writes d_out directly.
__global__ __launch_bounds__(256) void k_agg64(const float* __restrict__ z,
                                               const int* __restrict__ row_ptr,
                                               const int* __restrict__ csr_src,
                                               const float* __restrict__ norm_dst,
                                               const float* __restrict__ b3,
                                               float* __restrict__ out) {
    const int v = blockIdx.x * 4 + (threadIdx.x >> 6);
    const int f = threadIdx.x & 63;
    if (v >= NN) return;
    const int lo = row_ptr[v], hi = row_ptr[v + 1];
    float acc = 0.f;
    for (int i = lo; i < hi; ++i) {
        int s = csr_src[i];
        acc += z[(size_t)s * C3 + f];
    }
    out[(size_t)v * C3 + f] = acc * norm_dst[v] + b3[f];
}

// ---- GEMM -----------------------------------------------------------------
// C[m,n] = opt_relu( rowscale[m]*(A@W)[m,n] + bias[n] )
// A: MPAD x 1024 row-major, W: 1024 x N row-major. BM=128,BN=64,BK=16,
// 256 threads, 8x4 micro-tile.
__global__ __launch_bounds__(256) void k_gemm(const float* __restrict__ A,
                                              const float* __restrict__ W,
                                              const float* __restrict__ bias,
                                              const float* __restrict__ rowscale,
                                              float* __restrict__ C,
                                              int N, int relu) {
    __shared__ float As[16][128];   // [k][m]
    __shared__ float Bs[16][64];    // [k][n]
    const int t  = threadIdx.x;
    const int tx = t & 15, ty = t >> 4;
    const int m0 = blockIdx.x * 128;
    const int n0 = blockIdx.y * 64;

    const int lar = t >> 1;
    const int lac = (t & 1) * 8;
    const int lbr = t >> 4;
    const int lbc = (t & 15) * 4;

    const float* Ap = A + (size_t)(m0 + lar) * F + lac;
    const float* Wp = W + (size_t)lbr * N + n0 + lbc;

    float acc[8][4];
#pragma unroll
    for (int i = 0; i < 8; ++i)
#pragma unroll
        for (int j = 0; j < 4; ++j) acc[i][j] = 0.f;

    for (int kt = 0; kt < F; kt += 16) {
        float4 a0 = *(const float4*)(Ap + kt);
        float4 a1 = *(const float4*)(Ap + kt + 4);
        float4 wv = *(const float4*)(Wp + (size_t)kt * N);
        __syncthreads();
        As[lac + 0][lar] = a0.x; As[lac + 1][lar] = a0.y;
        As[lac + 2][lar] = a0.z; As[lac + 3][lar] = a0.w;
        As[lac + 4][lar] = a1.x; As[lac + 5][lar] = a1.y;
        As[lac + 6][lar] = a1.z; As[lac + 7][lar] = a1.w;
        *(float4*)&Bs[lbr][lbc] = wv;
        __syncthreads();
#pragma unroll
        for (int k = 0; k < 16; ++k) {
            float a[8], b[4];
#pragma unroll
            for (int i = 0; i < 8; ++i) a[i] = As[k][ty * 8 + i];
#pragma unroll
            for (int j = 0; j < 4; ++j) b[j] = Bs[k][tx * 4 + j];
#pragma unroll
            for (int i = 0; i < 8; ++i)
#pragma unroll
                for (int j = 0; j < 4; ++j)
                    acc[i][j] = fmaf(a[i], b[j], acc[i][j]);
        }
    }

    float bv[4];
#pragma unroll
    for (int j = 0; j < 4; ++j) bv[j] = bias ? bias[n0 + tx * 4 + j] : 0.f;
#pragma unroll
    for (int i = 0; i < 8; ++i) {
        int m = m0 + ty * 8 + i;
        float rs = rowscale[m];
        float4 o;
        o.x = acc[i][0] * rs + bv[0];
        o.y = acc[i][1] * rs + bv[1];
        o.z = acc[i][2] * rs + bv[2];
        o.w = acc[i][3] * rs + bv[3];
        if (relu) {
            o.x = fmaxf(o.x, 0.f); o.y = fmaxf(o.y, 0.f);
            o.z = fmaxf(o.z, 0.f); o.w = fmaxf(o.w, 0.f);
        }
        *(float4*)(C + (size_t)m * N + n0 + tx * 4) = o;
    }
}

// ---- driver ---------------------------------------------------------------

extern "C" void kernel_launch(void* const* d_in, const int* in_sizes, int n_in,
                              void* d_out, int out_size, void* d_ws, size_t ws_size,
                              hipStream_t stream) {
    const float* h   = (const float*)d_in[0];
    const int*   src = (const int*)d_in[1];
    const int*   dst = (const int*)d_in[2];
    const float* W1  = (const float*)d_in[3];
    const float* b1  = (const float*)d_in[4];
    const float* W2  = (const float*)d_in[5];
    const float* b2  = (const float*)d_in[6];
    const float* W3  = (const float*)d_in[7];
    const float* b3  = (const float*)d_in[8];
    float* out = (float*)d_out;

    char* ws = (char*)d_ws;
    int*   deg_out  = (int*)ws;                       ws += MPAD * 4;
    int*   deg_in   = (int*)ws;                       ws += MPAD * 4;
    float* norm_src = (float*)ws;                     ws += MPAD * 4;
    float* norm_dst = (float*)ws;                     ws += MPAD * 4;
    int*   row_ptr  = (int*)ws;                       ws += (NN + 1) * 4;
    int*   cursor   = (int*)ws;                       ws += NN * 4;
    int*   csr_src  = (int*)ws;                       ws += NE * 4;
    ws = (char*)(((size_t)ws + 255) & ~(size_t)255);
    float* agg      = (float*)ws;                     ws += (size_t)MPAD * F * 4;
    float* xbuf     = (float*)ws;                     ws += (size_t)MPAD * F * 4;
    float* z3       = (float*)ws;                     // MPAD * C3

    // CSR build + norms
    hipMemsetAsync(deg_out, 0, 2 * MPAD * sizeof(int), stream);
    k_degree<<<(NE + 255) / 256, 256, 0, stream>>>(src, dst, deg_out, deg_in);
    k_norm<<<(MPAD + 255) / 256, 256, 0, stream>>>(deg_out, deg_in, norm_src, norm_dst);
    k_scan<<<1, 1024, 0, stream>>>(deg_in, row_ptr, cursor);
    k_bucket<<<(NE + 255) / 256, 256, 0, stream>>>(src, dst, cursor, csr_src);

    // layer 1: agg = A(norm_src.*h); x1 = relu(norm_dst.*(agg@W1)+b1)
    k_agg1024<<<NN, 256, 0, stream>>>(h, row_ptr, csr_src, norm_src, agg);
    k_gemm<<<dim3(MPAD / 128, F / 64), 256, 0, stream>>>(agg, W1, b1, norm_dst, xbuf, F, 1);

    // layer 2
    k_agg1024<<<NN, 256, 0, stream>>>(xbuf, row_ptr, csr_src, norm_src, agg);
    k_gemm<<<dim3(MPAD / 128, F / 64), 256, 0, stream>>>(agg, W2, b2, norm_dst, xbuf, F, 1);

    // layer 3 reordered: z3=(norm_src.*x2)@W3 ; out = norm_dst.*(A z3) + b3
    k_gemm<<<dim3(MPAD / 128, 1), 256, 0, stream>>>(xbuf, W3, nullptr, norm_src, z3, C3, 0);
    k_agg64<<<(NN + 3) / 4, 256, 0, stream>>>(z3, row_ptr, csr_src, norm_dst, b3, out);
}

// Round 3
// 507.419 us; speedup vs baseline: 10.0342x; 1.8259x over previous
//
#include <hip/hip_runtime.h>

// GCN: 3 x (gather-aggregate via CSR -> GEMM(+bias,+relu))
// R1: CSR gather aggregation (no fp32 atomics).
// R2: layers 1&2 GEMM -> bf16 MFMA (16x16x32), global_load_lds width-16
//     staging, XOR-swizzled LDS (2-way bank alias = free). W1/W2 transposed
//     +converted to bf16 [n][k] once per launch. agg written as bf16.
constexpr int NN   = 10000;
constexpr int NE   = 160000;
constexpr int F    = 1024;
constexpr int C3   = 64;
constexpr int MPAD = 10112;   // 79 * 128

typedef __attribute__((ext_vector_type(8))) short short8;
typedef __attribute__((ext_vector_type(4))) float floatx4;

__device__ __forceinline__ unsigned short f2bf(float f) {
    union { float f; unsigned u; } v; v.f = f;
    unsigned r = v.u + 0x7fff + ((v.u >> 16) & 1);   // RNE
    return (unsigned short)(r >> 16);
}

__device__ __forceinline__ void gl_lds16(const void* g, void* l) {
    __builtin_amdgcn_global_load_lds(
        (const __attribute__((address_space(1))) unsigned int*)g,
        (__attribute__((address_space(3))) unsigned int*)l, 16, 0, 0);
}

// ---- CSR build ------------------------------------------------------------

__global__ __launch_bounds__(256) void k_degree(const int* __restrict__ src,
                                                const int* __restrict__ dst,
                                                int* __restrict__ deg_out,
                                                int* __restrict__ deg_in) {
    int e = blockIdx.x * 256 + threadIdx.x;
    if (e < NE) {
        atomicAdd(&deg_out[src[e]], 1);
        atomicAdd(&deg_in[dst[e]], 1);
    }
}

__global__ __launch_bounds__(256) void k_norm(const int* __restrict__ deg_out,
                                              const int* __restrict__ deg_in,
                                              float* __restrict__ norm_src,
                                              float* __restrict__ norm_dst) {
    int v = blockIdx.x * 256 + threadIdx.x;
    if (v < MPAD) {
        norm_src[v] = rsqrtf(fmaxf((float)deg_out[v], 1.0f));
        norm_dst[v] = rsqrtf(fmaxf((float)deg_in[v], 1.0f));
    }
}

__global__ __launch_bounds__(1024) void k_scan(const int* __restrict__ deg_in,
                                               int* __restrict__ row_ptr,
                                               int* __restrict__ cursor) {
    constexpr int CH = 10;
    __shared__ int sums[1024];
    const int tid = threadIdx.x;
    int local[CH];
    int tsum = 0;
#pragma unroll
    for (int j = 0; j < CH; ++j) {
        int idx = tid * CH + j;
        int v = (idx < NN) ? deg_in[idx] : 0;
        local[j] = v;
        tsum += v;
    }
    sums[tid] = tsum;
    __syncthreads();
    for (int off = 1; off < 1024; off <<= 1) {
        int v = (tid >= off) ? sums[tid - off] : 0;
        __syncthreads();
        sums[tid] += v;
        __syncthreads();
    }
    int run = sums[tid] - tsum;
#pragma unroll
    for (int j = 0; j < CH; ++j) {
        int idx = tid * CH + j;
        if (idx < NN) {
            row_ptr[idx] = run;
            cursor[idx]  = run;
        }
        run += local[j];
    }
    if (tid == 1023) row_ptr[NN] = sums[1023];
}

__global__ __launch_bounds__(256) void k_bucket(const int* __restrict__ src,
                                                const int* __restrict__ dst,
                                                int* __restrict__ cursor,
                                                int* __restrict__ csr_src) {
    int e = blockIdx.x * 256 + threadIdx.x;
    if (e < NE) {
        int slot = atomicAdd(&cursor[dst[e]], 1);
        csr_src[slot] = src[e];
    }
}

// ---- weight transpose+convert: W[k][n] fp32 -> Wt[n][k] bf16 --------------

__global__ __launch_bounds__(256) void k_wconv(const float* __restrict__ W,
                                               unsigned short* __restrict__ Wt) {
    __shared__ float tile[32][33];
    const int n0 = blockIdx.x * 32, k0 = blockIdx.y * 32;
    const int tx = threadIdx.x & 31, ty = threadIdx.x >> 5;   // 32 x 8
#pragma unroll
    for (int i = 0; i < 32; i += 8)
        tile[ty + i][tx] = W[(size_t)(k0 + ty + i) * F + n0 + tx];  // [k][n]
    __syncthreads();
#pragma unroll
    for (int i = 0; i < 32; i += 8)
        Wt[(size_t)(n0 + ty + i) * F + k0 + tx] = f2bf(tile[tx][ty + i]);
}

// ---- aggregation (gather), bf16 output ------------------------------------

__global__ __launch_bounds__(256) void k_agg1024b(const float* __restrict__ x,
                                                  const int* __restrict__ row_ptr,
                                                  const int* __restrict__ csr_src,
                                                  const float* __restrict__ norm_src,
                                                  unsigned short* __restrict__ aggb) {
    const int v  = blockIdx.x;
    const int t  = threadIdx.x;
    const int lo = row_ptr[v], hi = row_ptr[v + 1];
    float4 acc = {0.f, 0.f, 0.f, 0.f};
    for (int i = lo; i < hi; ++i) {
        int s = csr_src[i];
        float ns = norm_src[s];
        float4 xv = ((const float4*)(x + (size_t)s * F))[t];
        acc.x = fmaf(ns, xv.x, acc.x);
        acc.y = fmaf(ns, xv.y, acc.y);
        acc.z = fmaf(ns, xv.z, acc.z);
        acc.w = fmaf(ns, xv.w, acc.w);
    }
    ushort4 o;
    o.x = f2bf(acc.x); o.y = f2bf(acc.y); o.z = f2bf(acc.z); o.w = f2bf(acc.w);
    ((ushort4*)(aggb + (size_t)v * F))[t] = o;
}

// layer-3 aggregation, 64 feats, fused epilogue, writes d_out
__global__ __launch_bounds__(256) void k_agg64(const float* __restrict__ z,
                                               const int* __restrict__ row_ptr,
                                               const int* __restrict__ csr_src,
                                               const float* __restrict__ norm_dst,
                                               const float* __restrict__ b3,
                                               float* __restrict__ out) {
    const int v = blockIdx.x * 4 + (threadIdx.x >> 6);
    const int f = threadIdx.x & 63;
    if (v >= NN) return;
    const int lo = row_ptr[v], hi = row_ptr[v + 1];
    float acc = 0.f;
    for (int i = lo; i < hi; ++i) {
        int s = csr_src[i];
        acc += z[(size_t)s * C3 + f];
    }
    out[(size_t)v * C3 + f] = acc * norm_dst[v] + b3[f];
}

// ---- bf16 MFMA GEMM: C = relu?( rowscale[m]*(A@Bt^T)[m,n] + bias[n] ) -----
// A: [MPAD][1024] bf16 row-major. Bt: [1024 n][1024 k] bf16 (W transposed).
// 128x128 tile, 4 waves x (64x64), 16x16x32 MFMA, BK=32.
// LDS swizzle: 16B k-chunk kq stored at slot kq ^ ((row>>1)&3) -> every
// ds_read_b128 is exactly 2-way bank-aliased (free, m136) while keeping the
// lane-contiguous dest global_load_lds requires.
__global__ __launch_bounds__(256) void k_gemm_bf16(
        const unsigned short* __restrict__ A,
        const unsigned short* __restrict__ Bt,
        const float* __restrict__ bias,
        const float* __restrict__ rowscale,
        float* __restrict__ C,
        int relu) {
    __shared__ short As[128 * 32];
    __shared__ short Bs[128 * 32];
    const int t = threadIdx.x, lane = t & 63, wid = t >> 6;
    const int m0 = blockIdx.x * 128, n0 = blockIdx.y * 128;
    const int wm0 = (wid & 1) * 64, wn0 = (wid >> 1) * 64;
    const int lr = lane & 15, q = lane >> 4;

    // staging: wave handles tile-instrs {wid, wid+4}; lane l -> row i*16+l/4,
    // dest k-chunk l%4, source k-chunk swizzled.
    int srow[2], soff[2];
#pragma unroll
    for (int j = 0; j < 2; ++j) {
        int i = wid + j * 4;
        int r = i * 16 + (lane >> 2);
        srow[j] = r;
        soff[j] = (((lane & 3) ^ ((r >> 1) & 3)) * 8);
    }
    const unsigned short* aSrc0 = A  + (size_t)(m0 + srow[0]) * F + soff[0];
    const unsigned short* aSrc1 = A  + (size_t)(m0 + srow[1]) * F + soff[1];
    const unsigned short* bSrc0 = Bt + (size_t)(n0 + srow[0]) * F + soff[0];
    const unsigned short* bSrc1 = Bt + (size_t)(n0 + srow[1]) * F + soff[1];
    short* aDst0 = &As[(wid)     * 512];
    short* aDst1 = &As[(wid + 4) * 512];
    short* bDst0 = &Bs[(wid)     * 512];
    short* bDst1 = &Bs[(wid + 4) * 512];

    // ds_read fragment pointers (constant across K-loop)
    const short* ap[4];
    const short* bp[4];
#pragma unroll
    for (int mb = 0; mb < 4; ++mb) {
        int m = wm0 + mb * 16 + lr;
        ap[mb] = &As[m * 32 + (q ^ ((m >> 1) & 3)) * 8];
        int n = wn0 + mb * 16 + lr;
        bp[mb] = &Bs[n * 32 + (q ^ ((n >> 1) & 3)) * 8];
    }

    floatx4 acc[4][4] = {};

    for (int k0 = 0; k0 < F; k0 += 32) {
        __syncthreads();
        gl_lds16(aSrc0 + k0, aDst0);
        gl_lds16(aSrc1 + k0, aDst1);
        gl_lds16(bSrc0 + k0, bDst0);
        gl_lds16(bSrc1 + k0, bDst1);
        __syncthreads();
        short8 af[4], bf[4];
#pragma unroll
        for (int mb = 0; mb < 4; ++mb) af[mb] = *(const short8*)ap[mb];
#pragma unroll
        for (int nb = 0; nb < 4; ++nb) bf[nb] = *(const short8*)bp[nb];
#pragma unroll
        for (int mb = 0; mb < 4; ++mb)
#pragma unroll
            for (int nb = 0; nb < 4; ++nb)
                acc[mb][nb] = __builtin_amdgcn_mfma_f32_16x16x32_bf16(
                    af[mb], bf[nb], acc[mb][nb], 0, 0, 0);
    }

    // epilogue: D[row=(q*4+r)+mb*16+wm0][col=lr+nb*16+wn0]
    float rs[4][4];
#pragma unroll
    for (int mb = 0; mb < 4; ++mb)
#pragma unroll
        for (int r = 0; r < 4; ++r)
            rs[mb][r] = rowscale[m0 + wm0 + mb * 16 + q * 4 + r];
#pragma unroll
    for (int nb = 0; nb < 4; ++nb) {
        int col = n0 + wn0 + nb * 16 + lr;
        float bv = bias[col];
#pragma unroll
        for (int mb = 0; mb < 4; ++mb)
#pragma unroll
            for (int r = 0; r < 4; ++r) {
                int row = m0 + wm0 + mb * 16 + q * 4 + r;
                float v = acc[mb][nb][r] * rs[mb][r] + bv;
                if (relu) v = fmaxf(v, 0.f);
                C[(size_t)row * F + col] = v;
            }
    }
}

// ---- fp32 GEMM (layer 3 only: N=64) ---------------------------------------
__global__ __launch_bounds__(256) void k_gemm(const float* __restrict__ A,
                                              const float* __restrict__ W,
                                              const float* __restrict__ bias,
                                              const float* __restrict__ rowscale,
                                              float* __restrict__ C,
                                              int N, int relu) {
    __shared__ float Asf[16][128];
    __shared__ float Bsf[16][64];
    const int t  = threadIdx.x;
    const int tx = t & 15, ty = t >> 4;
    const int m0 = blockIdx.x * 128;
    const int n0 = blockIdx.y * 64;

    const int lar = t >> 1;
    const int lac = (t & 1) * 8;
    const int lbr = t >> 4;
    const int lbc = (t & 15) * 4;

    const float* Ap = A + (size_t)(m0 + lar) * F + lac;
    const float* Wp = W + (size_t)lbr * N + n0 + lbc;

    float acc[8][4];
#pragma unroll
    for (int i = 0; i < 8; ++i)
#pragma unroll
        for (int j = 0; j < 4; ++j) acc[i][j] = 0.f;

    for (int kt = 0; kt < F; kt += 16) {
        float4 a0 = *(const float4*)(Ap + kt);
        float4 a1 = *(const float4*)(Ap + kt + 4);
        float4 wv = *(const float4*)(Wp + (size_t)kt * N);
        __syncthreads();
        Asf[lac + 0][lar] = a0.x; Asf[lac + 1][lar] = a0.y;
        Asf[lac + 2][lar] = a0.z; Asf[lac + 3][lar] = a0.w;
        Asf[lac + 4][lar] = a1.x; Asf[lac + 5][lar] = a1.y;
        Asf[lac + 6][lar] = a1.z; Asf[lac + 7][lar] = a1.w;
        *(float4*)&Bsf[lbr][lbc] = wv;
        __syncthreads();
#pragma unroll
        for (int k = 0; k < 16; ++k) {
            float a[8], b[4];
#pragma unroll
            for (int i = 0; i < 8; ++i) a[i] = Asf[k][ty * 8 + i];
#pragma unroll
            for (int j = 0; j < 4; ++j) b[j] = Bsf[k][tx * 4 + j];
#pragma unroll
            for (int i = 0; i < 8; ++i)
#pragma unroll
                for (int j = 0; j < 4; ++j)
                    acc[i][j] = fmaf(a[i], b[j], acc[i][j]);
        }
    }

    float bv[4];
#pragma unroll
    for (int j = 0; j < 4; ++j) bv[j] = bias ? bias[n0 + tx * 4 + j] : 0.f;
#pragma unroll
    for (int i = 0; i < 8; ++i) {
        int m = m0 + ty * 8 + i;
        float rsv = rowscale[m];
        float4 o;
        o.x = acc[i][0] * rsv + bv[0];
        o.y = acc[i][1] * rsv + bv[1];
        o.z = acc[i][2] * rsv + bv[2];
        o.w = acc[i][3] * rsv + bv[3];
        if (relu) {
            o.x = fmaxf(o.x, 0.f); o.y = fmaxf(o.y, 0.f);
            o.z = fmaxf(o.z, 0.f); o.w = fmaxf(o.w, 0.f);
        }
        *(float4*)(C + (size_t)m * N + n0 + tx * 4) = o;
    }
}

// ---- driver ---------------------------------------------------------------

extern "C" void kernel_launch(void* const* d_in, const int* in_sizes, int n_in,
                              void* d_out, int out_size, void* d_ws, size_t ws_size,
                              hipStream_t stream) {
    const float* h   = (const float*)d_in[0];
    const int*   src = (const int*)d_in[1];
    const int*   dst = (const int*)d_in[2];
    const float* W1  = (const float*)d_in[3];
    const float* b1  = (const float*)d_in[4];
    const float* W2  = (const float*)d_in[5];
    const float* b2  = (const float*)d_in[6];
    const float* W3  = (const float*)d_in[7];
    const float* b3  = (const float*)d_in[8];
    float* out = (float*)d_out;

    char* ws = (char*)d_ws;
    int*   deg_out  = (int*)ws;                       ws += MPAD * 4;
    int*   deg_in   = (int*)ws;                       ws += MPAD * 4;
    float* norm_src = (float*)ws;                     ws += MPAD * 4;
    float* norm_dst = (float*)ws;                     ws += MPAD * 4;
    int*   row_ptr  = (int*)ws;                       ws += (NN + 1) * 4;
    int*   cursor   = (int*)ws;                       ws += NN * 4;
    int*   csr_src  = (int*)ws;                       ws += NE * 4;
    ws = (char*)(((size_t)ws + 255) & ~(size_t)255);
    unsigned short* aggb = (unsigned short*)ws;       ws += (size_t)MPAD * F * 2;
    unsigned short* Wt1  = (unsigned short*)ws;       ws += (size_t)F * F * 2;
    unsigned short* Wt2  = (unsigned short*)ws;       ws += (size_t)F * F * 2;
    float* xbuf     = (float*)ws;                     ws += (size_t)MPAD * F * 4;
    float* z3       = (float*)ws;                     // MPAD * C3 * 4

    // CSR build + norms + weight conversion
    hipMemsetAsync(deg_out, 0, 2 * MPAD * sizeof(int), stream);
    k_degree<<<(NE + 255) / 256, 256, 0, stream>>>(src, dst, deg_out, deg_in);
    k_norm<<<(MPAD + 255) / 256, 256, 0, stream>>>(deg_out, deg_in, norm_src, norm_dst);
    k_scan<<<1, 1024, 0, stream>>>(deg_in, row_ptr, cursor);
    k_bucket<<<(NE + 255) / 256, 256, 0, stream>>>(src, dst, cursor, csr_src);
    k_wconv<<<dim3(F / 32, F / 32), 256, 0, stream>>>(W1, Wt1);
    k_wconv<<<dim3(F / 32, F / 32), 256, 0, stream>>>(W2, Wt2);

    // layer 1
    k_agg1024b<<<NN, 256, 0, stream>>>(h, row_ptr, csr_src, norm_src, aggb);
    k_gemm_bf16<<<dim3(MPAD / 128, F / 128), 256, 0, stream>>>(aggb, Wt1, b1, norm_dst, xbuf, 1);

    // layer 2
    k_agg1024b<<<NN, 256, 0, stream>>>(xbuf, row_ptr, csr_src, norm_src, aggb);
    k_gemm_bf16<<<dim3(MPAD / 128, F / 128), 256, 0, stream>>>(aggb, Wt2, b2, norm_dst, xbuf, 1);

    // layer 3 reordered: z3=(norm_src.*x2)@W3 ; out = norm_dst.*(A z3) + b3
    k_gemm<<<dim3(MPAD / 128, 1), 256, 0, stream>>>(xbuf, W3, nullptr, norm_src, z3, C3, 0);
    k_agg64<<<(NN + 3) / 4, 256, 0, stream>>>(z3, row_ptr, csr_src, norm_dst, b3, out);
}

// Round 4
// 368.461 us; speedup vs baseline: 13.8184x; 1.3771x over previous
//
#include <hip/hip_runtime.h>

// GCN: 3 x (gather-aggregate via CSR -> GEMM(+bias,+relu))
// R1: CSR gather aggregation (no fp32 atomics).
// R2: layers 1&2 GEMM -> bf16 MFMA, global_load_lds(16) staging, XOR swizzle.
// R3: bf16 end-to-end (gather reads/writes bf16; GEMM1/2 emit ns-folded bf16),
//     layer-3 GEMM -> bf16 MFMA BM=64 (was fp32, 3.4% occupancy, 92us),
//     float4 k_agg64.
constexpr int NN   = 10000;
constexpr int NE   = 160000;
constexpr int F    = 1024;
constexpr int C3   = 64;
constexpr int MPAD = 10112;   // 79 * 128

typedef __attribute__((ext_vector_type(8))) short short8;
typedef __attribute__((ext_vector_type(8))) unsigned short ushort8v;
typedef __attribute__((ext_vector_type(4))) float floatx4;

__device__ __forceinline__ unsigned short f2bf(float f) {
    union { float f; unsigned u; } v; v.f = f;
    unsigned r = v.u + 0x7fff + ((v.u >> 16) & 1);   // RNE
    return (unsigned short)(r >> 16);
}
__device__ __forceinline__ float bf2f(unsigned short u) {
    union { unsigned u; float f; } v; v.u = ((unsigned)u) << 16;
    return v.f;
}

__device__ __forceinline__ void gl_lds16(const void* g, void* l) {
    __builtin_amdgcn_global_load_lds(
        (const __attribute__((address_space(1))) unsigned int*)g,
        (__attribute__((address_space(3))) unsigned int*)l, 16, 0, 0);
}

// ---- CSR build ------------------------------------------------------------

__global__ __launch_bounds__(256) void k_degree(const int* __restrict__ src,
                                                const int* __restrict__ dst,
                                                int* __restrict__ deg_out,
                                                int* __restrict__ deg_in) {
    int e = blockIdx.x * 256 + threadIdx.x;
    if (e < NE) {
        atomicAdd(&deg_out[src[e]], 1);
        atomicAdd(&deg_in[dst[e]], 1);
    }
}

__global__ __launch_bounds__(256) void k_norm(const int* __restrict__ deg_out,
                                              const int* __restrict__ deg_in,
                                              float* __restrict__ norm_src,
                                              float* __restrict__ norm_dst) {
    int v = blockIdx.x * 256 + threadIdx.x;
    if (v < MPAD) {
        norm_src[v] = rsqrtf(fmaxf((float)deg_out[v], 1.0f));
        norm_dst[v] = rsqrtf(fmaxf((float)deg_in[v], 1.0f));
    }
}

__global__ __launch_bounds__(1024) void k_scan(const int* __restrict__ deg_in,
                                               int* __restrict__ row_ptr,
                                               int* __restrict__ cursor) {
    constexpr int CH = 10;
    __shared__ int sums[1024];
    const int tid = threadIdx.x;
    int local[CH];
    int tsum = 0;
#pragma unroll
    for (int j = 0; j < CH; ++j) {
        int idx = tid * CH + j;
        int v = (idx < NN) ? deg_in[idx] : 0;
        local[j] = v;
        tsum += v;
    }
    sums[tid] = tsum;
    __syncthreads();
    for (int off = 1; off < 1024; off <<= 1) {
        int v = (tid >= off) ? sums[tid - off] : 0;
        __syncthreads();
        sums[tid] += v;
        __syncthreads();
    }
    int run = sums[tid] - tsum;
#pragma unroll
    for (int j = 0; j < CH; ++j) {
        int idx = tid * CH + j;
        if (idx < NN) {
            row_ptr[idx] = run;
            cursor[idx]  = run;
        }
        run += local[j];
    }
    if (tid == 1023) row_ptr[NN] = sums[1023];
}

__global__ __launch_bounds__(256) void k_bucket(const int* __restrict__ src,
                                                const int* __restrict__ dst,
                                                int* __restrict__ cursor,
                                                int* __restrict__ csr_src) {
    int e = blockIdx.x * 256 + threadIdx.x;
    if (e < NE) {
        int slot = atomicAdd(&cursor[dst[e]], 1);
        csr_src[slot] = src[e];
    }
}

// ---- weight transpose+convert: W[k][n] fp32 -> Wt[n][k] bf16 (k dim = F) --

__global__ __launch_bounds__(256) void k_wconv(const float* __restrict__ W,
                                               unsigned short* __restrict__ Wt,
                                               int N) {
    __shared__ float tile[32][33];
    const int n0 = blockIdx.x * 32, k0 = blockIdx.y * 32;
    const int tx = threadIdx.x & 31, ty = threadIdx.x >> 5;   // 32 x 8
#pragma unroll
    for (int i = 0; i < 32; i += 8)
        tile[ty + i][tx] = W[(size_t)(k0 + ty + i) * N + n0 + tx];  // [k][n]
    __syncthreads();
#pragma unroll
    for (int i = 0; i < 32; i += 8)
        Wt[(size_t)(n0 + ty + i) * F + k0 + tx] = f2bf(tile[tx][ty + i]);
}

// ---- h -> bf16 with norm_src fold: hb[v][f] = bf16(ns[v]*h[v][f]) ---------

__global__ __launch_bounds__(256) void k_hcvt(const float* __restrict__ h,
                                              const float* __restrict__ norm_src,
                                              unsigned short* __restrict__ hb) {
    int idx = blockIdx.x * 256 + threadIdx.x;     // NN*128 total
    int v = idx >> 7, f8 = (idx & 127) * 8;
    float ns = norm_src[v];
    const float4 a = *(const float4*)(h + (size_t)v * F + f8);
    const float4 b = *(const float4*)(h + (size_t)v * F + f8 + 4);
    ushort8v o;
    o[0] = f2bf(ns * a.x); o[1] = f2bf(ns * a.y);
    o[2] = f2bf(ns * a.z); o[3] = f2bf(ns * a.w);
    o[4] = f2bf(ns * b.x); o[5] = f2bf(ns * b.y);
    o[6] = f2bf(ns * b.z); o[7] = f2bf(ns * b.w);
    *(ushort8v*)(hb + (size_t)v * F + f8) = o;
}

// ---- aggregation: bf16 in, fp32 accumulate, bf16 out ----------------------
// 2 nodes per 256-thr block; 128 lanes x 8 bf16 (16B) per node.
// (source rows already carry norm_src)
__global__ __launch_bounds__(256) void k_aggb(const unsigned short* __restrict__ xb,
                                              const int* __restrict__ row_ptr,
                                              const int* __restrict__ csr_src,
                                              unsigned short* __restrict__ aggb) {
    const int v = blockIdx.x * 2 + (threadIdx.x >> 7);
    const int l = threadIdx.x & 127;
    const int lo = row_ptr[v], hi = row_ptr[v + 1];
    float acc[8] = {0.f, 0.f, 0.f, 0.f, 0.f, 0.f, 0.f, 0.f};
    for (int i = lo; i < hi; ++i) {
        int s = csr_src[i];
        ushort8v xv = *(const ushort8v*)(xb + (size_t)s * F + l * 8);
#pragma unroll
        for (int j = 0; j < 8; ++j) acc[j] += bf2f(xv[j]);
    }
    ushort8v o;
#pragma unroll
    for (int j = 0; j < 8; ++j) o[j] = f2bf(acc[j]);
    *(ushort8v*)(aggb + (size_t)v * F + l * 8) = o;
}

// layer-3 aggregation over z3 (fp32, 64 feats), fused nd/bias, writes d_out.
// 16 nodes per block, 16 lanes x float4 per node.
__global__ __launch_bounds__(256) void k_agg64(const float* __restrict__ z,
                                               const int* __restrict__ row_ptr,
                                               const int* __restrict__ csr_src,
                                               const float* __restrict__ norm_dst,
                                               const float* __restrict__ b3,
                                               float* __restrict__ out) {
    const int v = blockIdx.x * 16 + (threadIdx.x >> 4);
    if (v >= NN) return;
    const int f4 = (threadIdx.x & 15) * 4;
    const int lo = row_ptr[v], hi = row_ptr[v + 1];
    float4 acc = {0.f, 0.f, 0.f, 0.f};
    for (int i = lo; i < hi; ++i) {
        int s = csr_src[i];
        float4 zv = *(const float4*)(z + (size_t)s * C3 + f4);
        acc.x += zv.x; acc.y += zv.y; acc.z += zv.z; acc.w += zv.w;
    }
    float nd = norm_dst[v];
    float4 bv = *(const float4*)(b3 + f4);
    float4 o;
    o.x = acc.x * nd + bv.x; o.y = acc.y * nd + bv.y;
    o.z = acc.z * nd + bv.z; o.w = acc.w * nd + bv.w;
    *(float4*)(out + (size_t)v * C3 + f4) = o;
}

// ---- bf16 MFMA GEMM, layers 1&2 -------------------------------------------
// Cb[m][n] = bf16( rs2[m] * relu( rs1[m]*(A@Bt^T)[m,n] + bias[n] ) )
// A: [MPAD][F] bf16. Bt: [F n][F k] bf16. 128x128 tile, 4 waves x 64x64.
__global__ __launch_bounds__(256) void k_gemm_bf16(
        const unsigned short* __restrict__ A,
        const unsigned short* __restrict__ Bt,
        const float* __restrict__ bias,
        const float* __restrict__ rs1,   // norm_dst (pre-bias)
        const float* __restrict__ rs2,   // norm_src (post-relu)
        unsigned short* __restrict__ Cb) {
    __shared__ short As[128 * 32];
    __shared__ short Bs[128 * 32];
    const int t = threadIdx.x, lane = t & 63, wid = t >> 6;
    const int m0 = blockIdx.x * 128, n0 = blockIdx.y * 128;
    const int wm0 = (wid & 1) * 64, wn0 = (wid >> 1) * 64;
    const int lr = lane & 15, q = lane >> 4;

    int srow[2], soff[2];
#pragma unroll
    for (int j = 0; j < 2; ++j) {
        int i = wid + j * 4;
        int r = i * 16 + (lane >> 2);
        srow[j] = r;
        soff[j] = (((lane & 3) ^ ((r >> 1) & 3)) * 8);
    }
    const unsigned short* aSrc0 = A  + (size_t)(m0 + srow[0]) * F + soff[0];
    const unsigned short* aSrc1 = A  + (size_t)(m0 + srow[1]) * F + soff[1];
    const unsigned short* bSrc0 = Bt + (size_t)(n0 + srow[0]) * F + soff[0];
    const unsigned short* bSrc1 = Bt + (size_t)(n0 + srow[1]) * F + soff[1];
    short* aDst0 = &As[(wid)     * 512];
    short* aDst1 = &As[(wid + 4) * 512];
    short* bDst0 = &Bs[(wid)     * 512];
    short* bDst1 = &Bs[(wid + 4) * 512];

    const short* ap[4];
    const short* bp[4];
#pragma unroll
    for (int mb = 0; mb < 4; ++mb) {
        int m = wm0 + mb * 16 + lr;
        ap[mb] = &As[m * 32 + (q ^ ((m >> 1) & 3)) * 8];
        int n = wn0 + mb * 16 + lr;
        bp[mb] = &Bs[n * 32 + (q ^ ((n >> 1) & 3)) * 8];
    }

    floatx4 acc[4][4] = {};

    for (int k0 = 0; k0 < F; k0 += 32) {
        __syncthreads();
        gl_lds16(aSrc0 + k0, aDst0);
        gl_lds16(aSrc1 + k0, aDst1);
        gl_lds16(bSrc0 + k0, bDst0);
        gl_lds16(bSrc1 + k0, bDst1);
        __syncthreads();
        short8 af[4], bf[4];
#pragma unroll
        for (int mb = 0; mb < 4; ++mb) af[mb] = *(const short8*)ap[mb];
#pragma unroll
        for (int nb = 0; nb < 4; ++nb) bf[nb] = *(const short8*)bp[nb];
#pragma unroll
        for (int mb = 0; mb < 4; ++mb)
#pragma unroll
            for (int nb = 0; nb < 4; ++nb)
                acc[mb][nb] = __builtin_amdgcn_mfma_f32_16x16x32_bf16(
                    af[mb], bf[nb], acc[mb][nb], 0, 0, 0);
    }

    float s1[4][4], s2[4][4];
#pragma unroll
    for (int mb = 0; mb < 4; ++mb)
#pragma unroll
        for (int r = 0; r < 4; ++r) {
            int row = m0 + wm0 + mb * 16 + q * 4 + r;
            s1[mb][r] = rs1[row];
            s2[mb][r] = rs2[row];
        }
#pragma unroll
    for (int nb = 0; nb < 4; ++nb) {
        int col = n0 + wn0 + nb * 16 + lr;
        float bv = bias[col];
#pragma unroll
        for (int mb = 0; mb < 4; ++mb)
#pragma unroll
            for (int r = 0; r < 4; ++r) {
                int row = m0 + wm0 + mb * 16 + q * 4 + r;
                float v = fmaxf(acc[mb][nb][r] * s1[mb][r] + bv, 0.f) * s2[mb][r];
                Cb[(size_t)row * F + col] = f2bf(v);
            }
    }
}

// ---- bf16 MFMA GEMM, layer 3: z3 = x2' @ Wt3^T, fp32 out, N=64 ------------
// BM=64, 4 waves (wave w -> rows w*16..w*16+15, cols 0..63), grid MPAD/64.
__global__ __launch_bounds__(256) void k_gemm3(
        const unsigned short* __restrict__ A,
        const unsigned short* __restrict__ Bt,   // [64 n][F k]
        float* __restrict__ Z) {
    __shared__ short As3[64 * 32];
    __shared__ short Bs3[64 * 32];
    const int t = threadIdx.x, lane = t & 63, wid = t >> 6;
    const int m0 = blockIdx.x * 64;
    const int lr = lane & 15, q = lane >> 4;

    const int r = wid * 16 + (lane >> 2);
    const int soff = (((lane & 3) ^ ((r >> 1) & 3)) * 8);
    const unsigned short* aSrc = A  + (size_t)(m0 + r) * F + soff;
    const unsigned short* bSrc = Bt + (size_t)r * F + soff;
    short* aDst = &As3[wid * 512];
    short* bDst = &Bs3[wid * 512];

    const short* ap;
    {
        int m = wid * 16 + lr;
        ap = &As3[m * 32 + (q ^ ((m >> 1) & 3)) * 8];
    }
    const short* bp[4];
#pragma unroll
    for (int nb = 0; nb < 4; ++nb) {
        int n = nb * 16 + lr;
        bp[nb] = &Bs3[n * 32 + (q ^ ((n >> 1) & 3)) * 8];
    }

    floatx4 acc[4] = {};

    for (int k0 = 0; k0 < F; k0 += 32) {
        __syncthreads();
        gl_lds16(aSrc + k0, aDst);
        gl_lds16(bSrc + k0, bDst);
        __syncthreads();
        short8 af = *(const short8*)ap;
        short8 bf[4];
#pragma unroll
        for (int nb = 0; nb < 4; ++nb) bf[nb] = *(const short8*)bp[nb];
#pragma unroll
        for (int nb = 0; nb < 4; ++nb)
            acc[nb] = __builtin_amdgcn_mfma_f32_16x16x32_bf16(af, bf[nb], acc[nb], 0, 0, 0);
    }

#pragma unroll
    for (int nb = 0; nb < 4; ++nb) {
        int col = nb * 16 + lr;
#pragma unroll
        for (int ri = 0; ri < 4; ++ri) {
            int row = m0 + wid * 16 + q * 4 + ri;
            Z[(size_t)row * C3 + col] = acc[nb][ri];
        }
    }
}

// ---- driver ---------------------------------------------------------------

extern "C" void kernel_launch(void* const* d_in, const int* in_sizes, int n_in,
                              void* d_out, int out_size, void* d_ws, size_t ws_size,
                              hipStream_t stream) {
    const float* h   = (const float*)d_in[0];
    const int*   src = (const int*)d_in[1];
    const int*   dst = (const int*)d_in[2];
    const float* W1  = (const float*)d_in[3];
    const float* b1  = (const float*)d_in[4];
    const float* W2  = (const float*)d_in[5];
    const float* b2  = (const float*)d_in[6];
    const float* W3  = (const float*)d_in[7];
    const float* b3  = (const float*)d_in[8];
    float* out = (float*)d_out;

    char* ws = (char*)d_ws;
    int*   deg_out  = (int*)ws;                       ws += MPAD * 4;
    int*   deg_in   = (int*)ws;                       ws += MPAD * 4;
    float* norm_src = (float*)ws;                     ws += MPAD * 4;
    float* norm_dst = (float*)ws;                     ws += MPAD * 4;
    int*   row_ptr  = (int*)ws;                       ws += (NN + 1) * 4;
    int*   cursor   = (int*)ws;                       ws += NN * 4;
    int*   csr_src  = (int*)ws;                       ws += NE * 4;
    ws = (char*)(((size_t)ws + 255) & ~(size_t)255);
    unsigned short* hb   = (unsigned short*)ws;       ws += (size_t)MPAD * F * 2;
    unsigned short* aggb = (unsigned short*)ws;       ws += (size_t)MPAD * F * 2;
    unsigned short* xb   = (unsigned short*)ws;       ws += (size_t)MPAD * F * 2;
    unsigned short* Wt1  = (unsigned short*)ws;       ws += (size_t)F * F * 2;
    unsigned short* Wt2  = (unsigned short*)ws;       ws += (size_t)F * F * 2;
    unsigned short* Wt3  = (unsigned short*)ws;       ws += (size_t)C3 * F * 2;
    float* z3       = (float*)ws;                     // MPAD * C3 * 4

    // CSR build + norms + weight conversion + h conversion
    hipMemsetAsync(deg_out, 0, 2 * MPAD * sizeof(int), stream);
    k_degree<<<(NE + 255) / 256, 256, 0, stream>>>(src, dst, deg_out, deg_in);
    k_norm<<<(MPAD + 255) / 256, 256, 0, stream>>>(deg_out, deg_in, norm_src, norm_dst);
    k_scan<<<1, 1024, 0, stream>>>(deg_in, row_ptr, cursor);
    k_bucket<<<(NE + 255) / 256, 256, 0, stream>>>(src, dst, cursor, csr_src);
    k_wconv<<<dim3(F / 32, F / 32), 256, 0, stream>>>(W1, Wt1, F);
    k_wconv<<<dim3(F / 32, F / 32), 256, 0, stream>>>(W2, Wt2, F);
    k_wconv<<<dim3(C3 / 32, F / 32), 256, 0, stream>>>(W3, Wt3, C3);
    k_hcvt<<<NN * 128 / 256, 256, 0, stream>>>(h, norm_src, hb);

    // layer 1: aggb = Sum hb[src]; xb = bf16(ns.*relu(nd.*(aggb@W1)+b1))
    k_aggb<<<NN / 2, 256, 0, stream>>>(hb, row_ptr, csr_src, aggb);
    k_gemm_bf16<<<dim3(MPAD / 128, F / 128), 256, 0, stream>>>(aggb, Wt1, b1, norm_dst, norm_src, xb);

    // layer 2
    k_aggb<<<NN / 2, 256, 0, stream>>>(xb, row_ptr, csr_src, aggb);
    k_gemm_bf16<<<dim3(MPAD / 128, F / 128), 256, 0, stream>>>(aggb, Wt2, b2, norm_dst, norm_src, xb);

    // layer 3: z3 = xb @ W3t ; out = nd.*(A z3) + b3
    k_gemm3<<<MPAD / 64, 256, 0, stream>>>(xb, Wt3, z3);
    k_agg64<<<(NN + 15) / 16, 256, 0, stream>>>(z3, row_ptr, csr_src, norm_dst, b3, out);
}

// Round 5
// 315.456 us; speedup vs baseline: 16.1403x; 1.1680x over previous
//
#include <hip/hip_runtime.h>

// GCN: 3 x (gather-aggregate via CSR -> GEMM(+bias,+relu))
// R1: CSR gather aggregation (no fp32 atomics).
// R2: layers 1&2 GEMM -> bf16 MFMA, global_load_lds(16) staging, XOR swizzle.
// R3: bf16 end-to-end; layer-3 GEMM -> bf16 MFMA; fused epilogues.
// R4: (a) double-buffered LDS in MFMA GEMMs (barrier drains loads issued a
//         full iteration earlier -- matters at ~2.5 blocks/CU occupancy);
//     (b) XCD-partitioned gather: feature chunk c=blockIdx%8 -> per-XCD L2
//         slice is 2.56 MB < 4 MB, gather runs at L2 bandwidth.
constexpr int NN   = 10000;
constexpr int NE   = 160000;
constexpr int F    = 1024;
constexpr int C3   = 64;
constexpr int MPAD = 10112;   // 79 * 128

typedef __attribute__((ext_vector_type(8))) short short8;
typedef __attribute__((ext_vector_type(8))) unsigned short ushort8v;
typedef __attribute__((ext_vector_type(4))) float floatx4;

__device__ __forceinline__ unsigned short f2bf(float f) {
    union { float f; unsigned u; } v; v.f = f;
    unsigned r = v.u + 0x7fff + ((v.u >> 16) & 1);   // RNE
    return (unsigned short)(r >> 16);
}
__device__ __forceinline__ float bf2f(unsigned short u) {
    union { unsigned u; float f; } v; v.u = ((unsigned)u) << 16;
    return v.f;
}

__device__ __forceinline__ void gl_lds16(const void* g, void* l) {
    __builtin_amdgcn_global_load_lds(
        (const __attribute__((address_space(1))) unsigned int*)g,
        (__attribute__((address_space(3))) unsigned int*)l, 16, 0, 0);
}

// ---- CSR build ------------------------------------------------------------

__global__ __launch_bounds__(256) void k_degree(const int* __restrict__ src,
                                                const int* __restrict__ dst,
                                                int* __restrict__ deg_out,
                                                int* __restrict__ deg_in) {
    int e = blockIdx.x * 256 + threadIdx.x;
    if (e < NE) {
        atomicAdd(&deg_out[src[e]], 1);
        atomicAdd(&deg_in[dst[e]], 1);
    }
}

__global__ __launch_bounds__(256) void k_norm(const int* __restrict__ deg_out,
                                              const int* __restrict__ deg_in,
                                              float* __restrict__ norm_src,
                                              float* __restrict__ norm_dst) {
    int v = blockIdx.x * 256 + threadIdx.x;
    if (v < MPAD) {
        norm_src[v] = rsqrtf(fmaxf((float)deg_out[v], 1.0f));
        norm_dst[v] = rsqrtf(fmaxf((float)deg_in[v], 1.0f));
    }
}

__global__ __launch_bounds__(1024) void k_scan(const int* __restrict__ deg_in,
                                               int* __restrict__ row_ptr,
                                               int* __restrict__ cursor) {
    constexpr int CH = 10;
    __shared__ int sums[1024];
    const int tid = threadIdx.x;
    int local[CH];
    int tsum = 0;
#pragma unroll
    for (int j = 0; j < CH; ++j) {
        int idx = tid * CH + j;
        int v = (idx < NN) ? deg_in[idx] : 0;
        local[j] = v;
        tsum += v;
    }
    sums[tid] = tsum;
    __syncthreads();
    for (int off = 1; off < 1024; off <<= 1) {
        int v = (tid >= off) ? sums[tid - off] : 0;
        __syncthreads();
        sums[tid] += v;
        __syncthreads();
    }
    int run = sums[tid] - tsum;
#pragma unroll
    for (int j = 0; j < CH; ++j) {
        int idx = tid * CH + j;
        if (idx < NN) {
            row_ptr[idx] = run;
            cursor[idx]  = run;
        }
        run += local[j];
    }
    if (tid == 1023) row_ptr[NN] = sums[1023];
}

__global__ __launch_bounds__(256) void k_bucket(const int* __restrict__ src,
                                                const int* __restrict__ dst,
                                                int* __restrict__ cursor,
                                                int* __restrict__ csr_src) {
    int e = blockIdx.x * 256 + threadIdx.x;
    if (e < NE) {
        int slot = atomicAdd(&cursor[dst[e]], 1);
        csr_src[slot] = src[e];
    }
}

// ---- weight transpose+convert: W[k][n] fp32 -> Wt[n][k] bf16 (k dim = F) --

__global__ __launch_bounds__(256) void k_wconv(const float* __restrict__ W,
                                               unsigned short* __restrict__ Wt,
                                               int N) {
    __shared__ float tile[32][33];
    const int n0 = blockIdx.x * 32, k0 = blockIdx.y * 32;
    const int tx = threadIdx.x & 31, ty = threadIdx.x >> 5;   // 32 x 8
#pragma unroll
    for (int i = 0; i < 32; i += 8)
        tile[ty + i][tx] = W[(size_t)(k0 + ty + i) * N + n0 + tx];  // [k][n]
    __syncthreads();
#pragma unroll
    for (int i = 0; i < 32; i += 8)
        Wt[(size_t)(n0 + ty + i) * F + k0 + tx] = f2bf(tile[tx][ty + i]);
}

// ---- h -> bf16 with norm_src fold: hb[v][f] = bf16(ns[v]*h[v][f]) ---------

__global__ __launch_bounds__(256) void k_hcvt(const float* __restrict__ h,
                                              const float* __restrict__ norm_src,
                                              unsigned short* __restrict__ hb) {
    int idx = blockIdx.x * 256 + threadIdx.x;     // NN*128 total
    int v = idx >> 7, f8 = (idx & 127) * 8;
    float ns = norm_src[v];
    const float4 a = *(const float4*)(h + (size_t)v * F + f8);
    const float4 b = *(const float4*)(h + (size_t)v * F + f8 + 4);
    ushort8v o;
    o[0] = f2bf(ns * a.x); o[1] = f2bf(ns * a.y);
    o[2] = f2bf(ns * a.z); o[3] = f2bf(ns * a.w);
    o[4] = f2bf(ns * b.x); o[5] = f2bf(ns * b.y);
    o[6] = f2bf(ns * b.z); o[7] = f2bf(ns * b.w);
    *(ushort8v*)(hb + (size_t)v * F + f8) = o;
}

// ---- aggregation: bf16 in, fp32 accumulate, bf16 out ----------------------
// XCD-partitioned: chunk c = blockIdx%8 (rides round-robin block->XCD map),
// 128 feats per chunk -> per-XCD slice 10000*128*2B = 2.56 MB < 4 MB L2.
// 16 nodes per block, 16 lanes x 8 bf16 (16B) per node.
__global__ __launch_bounds__(256) void k_aggb(const unsigned short* __restrict__ xb,
                                              const int* __restrict__ row_ptr,
                                              const int* __restrict__ csr_src,
                                              unsigned short* __restrict__ aggb) {
    const int c = blockIdx.x & 7;                       // feature chunk -> XCD
    const int g = blockIdx.x >> 3;                      // node group
    const int v = g * 16 + (threadIdx.x >> 4);          // 625*16 == NN exactly
    const int f8 = c * 128 + (threadIdx.x & 15) * 8;
    const int lo = row_ptr[v], hi = row_ptr[v + 1];
    float acc[8] = {0.f, 0.f, 0.f, 0.f, 0.f, 0.f, 0.f, 0.f};
    for (int i = lo; i < hi; ++i) {
        int s = csr_src[i];
        ushort8v xv = *(const ushort8v*)(xb + (size_t)s * F + f8);
#pragma unroll
        for (int j = 0; j < 8; ++j) acc[j] += bf2f(xv[j]);
    }
    ushort8v o;
#pragma unroll
    for (int j = 0; j < 8; ++j) o[j] = f2bf(acc[j]);
    *(ushort8v*)(aggb + (size_t)v * F + f8) = o;
}

// layer-3 aggregation over z3 (fp32, 64 feats), fused nd/bias, writes d_out.
// 16 nodes per block, 16 lanes x float4 per node.
__global__ __launch_bounds__(256) void k_agg64(const float* __restrict__ z,
                                               const int* __restrict__ row_ptr,
                                               const int* __restrict__ csr_src,
                                               const float* __restrict__ norm_dst,
                                               const float* __restrict__ b3,
                                               float* __restrict__ out) {
    const int v = blockIdx.x * 16 + (threadIdx.x >> 4);
    if (v >= NN) return;
    const int f4 = (threadIdx.x & 15) * 4;
    const int lo = row_ptr[v], hi = row_ptr[v + 1];
    float4 acc = {0.f, 0.f, 0.f, 0.f};
    for (int i = lo; i < hi; ++i) {
        int s = csr_src[i];
        float4 zv = *(const float4*)(z + (size_t)s * C3 + f4);
        acc.x += zv.x; acc.y += zv.y; acc.z += zv.z; acc.w += zv.w;
    }
    float nd = norm_dst[v];
    float4 bv = *(const float4*)(b3 + f4);
    float4 o;
    o.x = acc.x * nd + bv.x; o.y = acc.y * nd + bv.y;
    o.z = acc.z * nd + bv.z; o.w = acc.w * nd + bv.w;
    *(float4*)(out + (size_t)v * C3 + f4) = o;
}

// ---- bf16 MFMA GEMM, layers 1&2, double-buffered --------------------------
// Cb[m][n] = bf16( rs2[m] * relu( rs1[m]*(A@Bt^T)[m,n] + bias[n] ) )
// A: [MPAD][F] bf16. Bt: [F n][F k] bf16. 128x128 tile, 4 waves x 64x64.
__global__ __launch_bounds__(256) void k_gemm_bf16(
        const unsigned short* __restrict__ A,
        const unsigned short* __restrict__ Bt,
        const float* __restrict__ bias,
        const float* __restrict__ rs1,   // norm_dst (pre-bias)
        const float* __restrict__ rs2,   // norm_src (post-relu)
        unsigned short* __restrict__ Cb) {
    __shared__ short As[2][128 * 32];
    __shared__ short Bs[2][128 * 32];
    const int t = threadIdx.x, lane = t & 63, wid = t >> 6;
    const int m0 = blockIdx.x * 128, n0 = blockIdx.y * 128;
    const int wm0 = (wid & 1) * 64, wn0 = (wid >> 1) * 64;
    const int lr = lane & 15, q = lane >> 4;

    int srow[2], soff[2];
#pragma unroll
    for (int j = 0; j < 2; ++j) {
        int i = wid + j * 4;
        int r = i * 16 + (lane >> 2);
        srow[j] = r;
        soff[j] = (((lane & 3) ^ ((r >> 1) & 3)) * 8);
    }
    const unsigned short* aSrc0 = A  + (size_t)(m0 + srow[0]) * F + soff[0];
    const unsigned short* aSrc1 = A  + (size_t)(m0 + srow[1]) * F + soff[1];
    const unsigned short* bSrc0 = Bt + (size_t)(n0 + srow[0]) * F + soff[0];
    const unsigned short* bSrc1 = Bt + (size_t)(n0 + srow[1]) * F + soff[1];

    const short* ap[4];
    const short* bp[4];
#pragma unroll
    for (int mb = 0; mb < 4; ++mb) {
        int m = wm0 + mb * 16 + lr;
        ap[mb] = &As[0][m * 32 + (q ^ ((m >> 1) & 3)) * 8];
        int n = wn0 + mb * 16 + lr;
        bp[mb] = &Bs[0][n * 32 + (q ^ ((n >> 1) & 3)) * 8];
    }

    floatx4 acc[4][4] = {};

    // prologue: stage tile 0 into buffer 0
    gl_lds16(aSrc0, &As[0][(wid)     * 512]);
    gl_lds16(aSrc1, &As[0][(wid + 4) * 512]);
    gl_lds16(bSrc0, &Bs[0][(wid)     * 512]);
    gl_lds16(bSrc1, &Bs[0][(wid + 4) * 512]);

    for (int kt = 0; kt < F / 32; ++kt) {
        const int buf = kt & 1;
        __syncthreads();                       // drains buf's loads (issued kt-1)
        if (kt + 1 < F / 32) {                 // prefetch next tile into other buf
            int k0 = (kt + 1) * 32;
            gl_lds16(aSrc0 + k0, &As[buf ^ 1][(wid)     * 512]);
            gl_lds16(aSrc1 + k0, &As[buf ^ 1][(wid + 4) * 512]);
            gl_lds16(bSrc0 + k0, &Bs[buf ^ 1][(wid)     * 512]);
            gl_lds16(bSrc1 + k0, &Bs[buf ^ 1][(wid + 4) * 512]);
        }
        const int bo = buf * (128 * 32);
        short8 af[4], bf[4];
#pragma unroll
        for (int mb = 0; mb < 4; ++mb) af[mb] = *(const short8*)(ap[mb] + bo);
#pragma unroll
        for (int nb = 0; nb < 4; ++nb) bf[nb] = *(const short8*)(bp[nb] + bo);
#pragma unroll
        for (int mb = 0; mb < 4; ++mb)
#pragma unroll
            for (int nb = 0; nb < 4; ++nb)
                acc[mb][nb] = __builtin_amdgcn_mfma_f32_16x16x32_bf16(
                    af[mb], bf[nb], acc[mb][nb], 0, 0, 0);
    }

    float s1[4][4], s2[4][4];
#pragma unroll
    for (int mb = 0; mb < 4; ++mb)
#pragma unroll
        for (int r = 0; r < 4; ++r) {
            int row = m0 + wm0 + mb * 16 + q * 4 + r;
            s1[mb][r] = rs1[row];
            s2[mb][r] = rs2[row];
        }
#pragma unroll
    for (int nb = 0; nb < 4; ++nb) {
        int col = n0 + wn0 + nb * 16 + lr;
        float bv = bias[col];
#pragma unroll
        for (int mb = 0; mb < 4; ++mb)
#pragma unroll
            for (int r = 0; r < 4; ++r) {
                int row = m0 + wm0 + mb * 16 + q * 4 + r;
                float v = fmaxf(acc[mb][nb][r] * s1[mb][r] + bv, 0.f) * s2[mb][r];
                Cb[(size_t)row * F + col] = f2bf(v);
            }
    }
}

// ---- bf16 MFMA GEMM, layer 3: z3 = x2' @ Wt3^T, fp32 out, N=64, dbuf ------
// BM=64, 4 waves (wave w -> rows w*16..w*16+15, cols 0..63), grid MPAD/64.
__global__ __launch_bounds__(256) void k_gemm3(
        const unsigned short* __restrict__ A,
        const unsigned short* __restrict__ Bt,   // [64 n][F k]
        float* __restrict__ Z) {
    __shared__ short As3[2][64 * 32];
    __shared__ short Bs3[2][64 * 32];
    const int t = threadIdx.x, lane = t & 63, wid = t >> 6;
    const int m0 = blockIdx.x * 64;
    const int lr = lane & 15, q = lane >> 4;

    const int r = wid * 16 + (lane >> 2);
    const int soff = (((lane & 3) ^ ((r >> 1) & 3)) * 8);
    const unsigned short* aSrc = A  + (size_t)(m0 + r) * F + soff;
    const unsigned short* bSrc = Bt + (size_t)r * F + soff;

    const short* ap;
    {
        int m = wid * 16 + lr;
        ap = &As3[0][m * 32 + (q ^ ((m >> 1) & 3)) * 8];
    }
    const short* bp[4];
#pragma unroll
    for (int nb = 0; nb < 4; ++nb) {
        int n = nb * 16 + lr;
        bp[nb] = &Bs3[0][n * 32 + (q ^ ((n >> 1) & 3)) * 8];
    }

    floatx4 acc[4] = {};

    gl_lds16(aSrc, &As3[0][wid * 512]);
    gl_lds16(bSrc, &Bs3[0][wid * 512]);

    for (int kt = 0; kt < F / 32; ++kt) {
        const int buf = kt & 1;
        __syncthreads();
        if (kt + 1 < F / 32) {
            int k0 = (kt + 1) * 32;
            gl_lds16(aSrc + k0, &As3[buf ^ 1][wid * 512]);
            gl_lds16(bSrc + k0, &Bs3[buf ^ 1][wid * 512]);
        }
        const int bo = buf * (64 * 32);
        short8 af = *(const short8*)(ap + bo);
        short8 bf[4];
#pragma unroll
        for (int nb = 0; nb < 4; ++nb) bf[nb] = *(const short8*)(bp[nb] + bo);
#pragma unroll
        for (int nb = 0; nb < 4; ++nb)
            acc[nb] = __builtin_amdgcn_mfma_f32_16x16x32_bf16(af, bf[nb], acc[nb], 0, 0, 0);
    }

#pragma unroll
    for (int nb = 0; nb < 4; ++nb) {
        int col = nb * 16 + lr;
#pragma unroll
        for (int ri = 0; ri < 4; ++ri) {
            int row = m0 + wid * 16 + q * 4 + ri;
            Z[(size_t)row * C3 + col] = acc[nb][ri];
        }
    }
}

// ---- driver ---------------------------------------------------------------

extern "C" void kernel_launch(void* const* d_in, const int* in_sizes, int n_in,
                              void* d_out, int out_size, void* d_ws, size_t ws_size,
                              hipStream_t stream) {
    const float* h   = (const float*)d_in[0];
    const int*   src = (const int*)d_in[1];
    const int*   dst = (const int*)d_in[2];
    const float* W1  = (const float*)d_in[3];
    const float* b1  = (const float*)d_in[4];
    const float* W2  = (const float*)d_in[5];
    const float* b2  = (const float*)d_in[6];
    const float* W3  = (const float*)d_in[7];
    const float* b3  = (const float*)d_in[8];
    float* out = (float*)d_out;

    char* ws = (char*)d_ws;
    int*   deg_out  = (int*)ws;                       ws += MPAD * 4;
    int*   deg_in   = (int*)ws;                       ws += MPAD * 4;
    float* norm_src = (float*)ws;                     ws += MPAD * 4;
    float* norm_dst = (float*)ws;                     ws += MPAD * 4;
    int*   row_ptr  = (int*)ws;                       ws += (NN + 1) * 4;
    int*   cursor   = (int*)ws;                       ws += NN * 4;
    int*   csr_src  = (int*)ws;                       ws += NE * 4;
    ws = (char*)(((size_t)ws + 255) & ~(size_t)255);
    unsigned short* hb   = (unsigned short*)ws;       ws += (size_t)MPAD * F * 2;
    unsigned short* aggb = (unsigned short*)ws;       ws += (size_t)MPAD * F * 2;
    unsigned short* xb   = (unsigned short*)ws;       ws += (size_t)MPAD * F * 2;
    unsigned short* Wt1  = (unsigned short*)ws;       ws += (size_t)F * F * 2;
    unsigned short* Wt2  = (unsigned short*)ws;       ws += (size_t)F * F * 2;
    unsigned short* Wt3  = (unsigned short*)ws;       ws += (size_t)C3 * F * 2;
    float* z3       = (float*)ws;                     // MPAD * C3 * 4

    // CSR build + norms + weight conversion + h conversion
    hipMemsetAsync(deg_out, 0, 2 * MPAD * sizeof(int), stream);
    k_degree<<<(NE + 255) / 256, 256, 0, stream>>>(src, dst, deg_out, deg_in);
    k_norm<<<(MPAD + 255) / 256, 256, 0, stream>>>(deg_out, deg_in, norm_src, norm_dst);
    k_scan<<<1, 1024, 0, stream>>>(deg_in, row_ptr, cursor);
    k_bucket<<<(NE + 255) / 256, 256, 0, stream>>>(src, dst, cursor, csr_src);
    k_wconv<<<dim3(F / 32, F / 32), 256, 0, stream>>>(W1, Wt1, F);
    k_wconv<<<dim3(F / 32, F / 32), 256, 0, stream>>>(W2, Wt2, F);
    k_wconv<<<dim3(C3 / 32, F / 32), 256, 0, stream>>>(W3, Wt3, C3);
    k_hcvt<<<NN * 128 / 256, 256, 0, stream>>>(h, norm_src, hb);

    // layer 1: aggb = Sum hb[src]; xb = bf16(ns.*relu(nd.*(aggb@W1)+b1))
    k_aggb<<<(NN / 16) * 8, 256, 0, stream>>>(hb, row_ptr, csr_src, aggb);
    k_gemm_bf16<<<dim3(MPAD / 128, F / 128), 256, 0, stream>>>(aggb, Wt1, b1, norm_dst, norm_src, xb);

    // layer 2
    k_aggb<<<(NN / 16) * 8, 256, 0, stream>>>(xb, row_ptr, csr_src, aggb);
    k_gemm_bf16<<<dim3(MPAD / 128, F / 128), 256, 0, stream>>>(aggb, Wt2, b2, norm_dst, norm_src, xb);

    // layer 3: z3 = xb @ W3t ; out = nd.*(A z3) + b3
    k_gemm3<<<MPAD / 64, 256, 0, stream>>>(xb, Wt3, z3);
    k_agg64<<<(NN + 15) / 16, 256, 0, stream>>>(z3, row_ptr, csr_src, norm_dst, b3, out);
}

// Round 6
// 302.228 us; speedup vs baseline: 16.8467x; 1.0438x over previous
//
#include <hip/hip_runtime.h>

// GCN: 3 x (gather-aggregate via CSR -> GEMM(+bias,+relu))
// R1: CSR gather aggregation (no fp32 atomics).
// R2: layers 1&2 GEMM -> bf16 MFMA, global_load_lds(16) staging, XOR swizzle.
// R3: bf16 end-to-end; layer-3 GEMM -> bf16 MFMA; fused epilogues.
// R4: double-buffered LDS in MFMA GEMMs; XCD-partitioned gather.
// R5: XCD-locality GEMM grid swizzle: 1-D grid, each XCD owns ~10 contiguous
//     m-slabs x all n  -> per-XCD working set ~4.75 MB ~ L2, A fetched once
//     per owning XCD (was 8x -> 89.5 MB HBM). k_aggb edge-loop unroll x2.
constexpr int NN   = 10000;
constexpr int NE   = 160000;
constexpr int F    = 1024;
constexpr int C3   = 64;
constexpr int MPAD = 10112;   // 79 * 128

typedef __attribute__((ext_vector_type(8))) short short8;
typedef __attribute__((ext_vector_type(8))) unsigned short ushort8v;
typedef __attribute__((ext_vector_type(4))) float floatx4;

__device__ __forceinline__ unsigned short f2bf(float f) {
    union { float f; unsigned u; } v; v.f = f;
    unsigned r = v.u + 0x7fff + ((v.u >> 16) & 1);   // RNE
    return (unsigned short)(r >> 16);
}
__device__ __forceinline__ float bf2f(unsigned short u) {
    union { unsigned u; float f; } v; v.u = ((unsigned)u) << 16;
    return v.f;
}

__device__ __forceinline__ void gl_lds16(const void* g, void* l) {
    __builtin_amdgcn_global_load_lds(
        (const __attribute__((address_space(1))) unsigned int*)g,
        (__attribute__((address_space(3))) unsigned int*)l, 16, 0, 0);
}

// ---- CSR build ------------------------------------------------------------

__global__ __launch_bounds__(256) void k_degree(const int* __restrict__ src,
                                                const int* __restrict__ dst,
                                                int* __restrict__ deg_out,
                                                int* __restrict__ deg_in) {
    int e = blockIdx.x * 256 + threadIdx.x;
    if (e < NE) {
        atomicAdd(&deg_out[src[e]], 1);
        atomicAdd(&deg_in[dst[e]], 1);
    }
}

__global__ __launch_bounds__(256) void k_norm(const int* __restrict__ deg_out,
                                              const int* __restrict__ deg_in,
                                              float* __restrict__ norm_src,
                                              float* __restrict__ norm_dst) {
    int v = blockIdx.x * 256 + threadIdx.x;
    if (v < MPAD) {
        norm_src[v] = rsqrtf(fmaxf((float)deg_out[v], 1.0f));
        norm_dst[v] = rsqrtf(fmaxf((float)deg_in[v], 1.0f));
    }
}

__global__ __launch_bounds__(1024) void k_scan(const int* __restrict__ deg_in,
                                               int* __restrict__ row_ptr,
                                               int* __restrict__ cursor) {
    constexpr int CH = 10;
    __shared__ int sums[1024];
    const int tid = threadIdx.x;
    int local[CH];
    int tsum = 0;
#pragma unroll
    for (int j = 0; j < CH; ++j) {
        int idx = tid * CH + j;
        int v = (idx < NN) ? deg_in[idx] : 0;
        local[j] = v;
        tsum += v;
    }
    sums[tid] = tsum;
    __syncthreads();
    for (int off = 1; off < 1024; off <<= 1) {
        int v = (tid >= off) ? sums[tid - off] : 0;
        __syncthreads();
        sums[tid] += v;
        __syncthreads();
    }
    int run = sums[tid] - tsum;
#pragma unroll
    for (int j = 0; j < CH; ++j) {
        int idx = tid * CH + j;
        if (idx < NN) {
            row_ptr[idx] = run;
            cursor[idx]  = run;
        }
        run += local[j];
    }
    if (tid == 1023) row_ptr[NN] = sums[1023];
}

__global__ __launch_bounds__(256) void k_bucket(const int* __restrict__ src,
                                                const int* __restrict__ dst,
                                                int* __restrict__ cursor,
                                                int* __restrict__ csr_src) {
    int e = blockIdx.x * 256 + threadIdx.x;
    if (e < NE) {
        int slot = atomicAdd(&cursor[dst[e]], 1);
        csr_src[slot] = src[e];
    }
}

// ---- weight transpose+convert: W[k][n] fp32 -> Wt[n][k] bf16 (k dim = F) --

__global__ __launch_bounds__(256) void k_wconv(const float* __restrict__ W,
                                               unsigned short* __restrict__ Wt,
                                               int N) {
    __shared__ float tile[32][33];
    const int n0 = blockIdx.x * 32, k0 = blockIdx.y * 32;
    const int tx = threadIdx.x & 31, ty = threadIdx.x >> 5;   // 32 x 8
#pragma unroll
    for (int i = 0; i < 32; i += 8)
        tile[ty + i][tx] = W[(size_t)(k0 + ty + i) * N + n0 + tx];  // [k][n]
    __syncthreads();
#pragma unroll
    for (int i = 0; i < 32; i += 8)
        Wt[(size_t)(n0 + ty + i) * F + k0 + tx] = f2bf(tile[tx][ty + i]);
}

// ---- h -> bf16 with norm_src fold: hb[v][f] = bf16(ns[v]*h[v][f]) ---------

__global__ __launch_bounds__(256) void k_hcvt(const float* __restrict__ h,
                                              const float* __restrict__ norm_src,
                                              unsigned short* __restrict__ hb) {
    int idx = blockIdx.x * 256 + threadIdx.x;     // NN*128 total
    int v = idx >> 7, f8 = (idx & 127) * 8;
    float ns = norm_src[v];
    const float4 a = *(const float4*)(h + (size_t)v * F + f8);
    const float4 b = *(const float4*)(h + (size_t)v * F + f8 + 4);
    ushort8v o;
    o[0] = f2bf(ns * a.x); o[1] = f2bf(ns * a.y);
    o[2] = f2bf(ns * a.z); o[3] = f2bf(ns * a.w);
    o[4] = f2bf(ns * b.x); o[5] = f2bf(ns * b.y);
    o[6] = f2bf(ns * b.z); o[7] = f2bf(ns * b.w);
    *(ushort8v*)(hb + (size_t)v * F + f8) = o;
}

// ---- aggregation: bf16 in, fp32 accumulate, bf16 out ----------------------
// XCD-partitioned: chunk c = blockIdx%8 (rides round-robin block->XCD map),
// 128 feats per chunk -> per-XCD slice 10000*128*2B = 2.56 MB < 4 MB L2.
// 16 nodes per block, 16 lanes x 8 bf16 (16B) per node. Edge loop unroll x2.
__global__ __launch_bounds__(256) void k_aggb(const unsigned short* __restrict__ xb,
                                              const int* __restrict__ row_ptr,
                                              const int* __restrict__ csr_src,
                                              unsigned short* __restrict__ aggb) {
    const int c = blockIdx.x & 7;                       // feature chunk -> XCD
    const int g = blockIdx.x >> 3;                      // node group
    const int v = g * 16 + (threadIdx.x >> 4);          // 625*16 == NN exactly
    const int f8 = c * 128 + (threadIdx.x & 15) * 8;
    const int lo = row_ptr[v], hi = row_ptr[v + 1];
    float acc[8] = {0.f, 0.f, 0.f, 0.f, 0.f, 0.f, 0.f, 0.f};
    int i = lo;
    for (; i + 2 <= hi; i += 2) {
        int s0 = csr_src[i], s1 = csr_src[i + 1];
        ushort8v x0 = *(const ushort8v*)(xb + (size_t)s0 * F + f8);
        ushort8v x1 = *(const ushort8v*)(xb + (size_t)s1 * F + f8);
#pragma unroll
        for (int j = 0; j < 8; ++j) acc[j] += bf2f(x0[j]);
#pragma unroll
        for (int j = 0; j < 8; ++j) acc[j] += bf2f(x1[j]);
    }
    if (i < hi) {
        int s = csr_src[i];
        ushort8v xv = *(const ushort8v*)(xb + (size_t)s * F + f8);
#pragma unroll
        for (int j = 0; j < 8; ++j) acc[j] += bf2f(xv[j]);
    }
    ushort8v o;
#pragma unroll
    for (int j = 0; j < 8; ++j) o[j] = f2bf(acc[j]);
    *(ushort8v*)(aggb + (size_t)v * F + f8) = o;
}

// layer-3 aggregation over z3 (fp32, 64 feats), fused nd/bias, writes d_out.
// 16 nodes per block, 16 lanes x float4 per node.
__global__ __launch_bounds__(256) void k_agg64(const float* __restrict__ z,
                                               const int* __restrict__ row_ptr,
                                               const int* __restrict__ csr_src,
                                               const float* __restrict__ norm_dst,
                                               const float* __restrict__ b3,
                                               float* __restrict__ out) {
    const int v = blockIdx.x * 16 + (threadIdx.x >> 4);
    if (v >= NN) return;
    const int f4 = (threadIdx.x & 15) * 4;
    const int lo = row_ptr[v], hi = row_ptr[v + 1];
    float4 acc = {0.f, 0.f, 0.f, 0.f};
    for (int i = lo; i < hi; ++i) {
        int s = csr_src[i];
        float4 zv = *(const float4*)(z + (size_t)s * C3 + f4);
        acc.x += zv.x; acc.y += zv.y; acc.z += zv.z; acc.w += zv.w;
    }
    float nd = norm_dst[v];
    float4 bv = *(const float4*)(b3 + f4);
    float4 o;
    o.x = acc.x * nd + bv.x; o.y = acc.y * nd + bv.y;
    o.z = acc.z * nd + bv.z; o.w = acc.w * nd + bv.w;
    *(float4*)(out + (size_t)v * C3 + f4) = o;
}

// ---- bf16 MFMA GEMM, layers 1&2, double-buffered, XCD-swizzled grid -------
// Cb[m][n] = bf16( rs2[m] * relu( rs1[m]*(A@Bt^T)[m,n] + bias[n] ) )
// A: [MPAD][F] bf16. Bt: [F n][F k] bf16. 128x128 tile, 4 waves x 64x64.
// 1-D grid 632; xcd=bid&7, each XCD owns a contiguous ~10-slab m-range x all
// n -> per-XCD L2 working set ~4.75 MB (A-slice 2.75 + B 2).
__global__ __launch_bounds__(256) void k_gemm_bf16(
        const unsigned short* __restrict__ A,
        const unsigned short* __restrict__ Bt,
        const float* __restrict__ bias,
        const float* __restrict__ rs1,   // norm_dst (pre-bias)
        const float* __restrict__ rs2,   // norm_src (post-relu)
        unsigned short* __restrict__ Cb) {
    const int bid = blockIdx.x;
    const int xcd = bid & 7, idx = bid >> 3;        // 8 x 79
    const int g   = xcd * 79 + idx;                 // contiguous tile run / XCD
    const int m0  = (g >> 3) * 128, n0 = (g & 7) * 128;

    __shared__ short As[2][128 * 32];
    __shared__ short Bs[2][128 * 32];
    const int t = threadIdx.x, lane = t & 63, wid = t >> 6;
    const int wm0 = (wid & 1) * 64, wn0 = (wid >> 1) * 64;
    const int lr = lane & 15, q = lane >> 4;

    int srow[2], soff[2];
#pragma unroll
    for (int j = 0; j < 2; ++j) {
        int i = wid + j * 4;
        int r = i * 16 + (lane >> 2);
        srow[j] = r;
        soff[j] = (((lane & 3) ^ ((r >> 1) & 3)) * 8);
    }
    const unsigned short* aSrc0 = A  + (size_t)(m0 + srow[0]) * F + soff[0];
    const unsigned short* aSrc1 = A  + (size_t)(m0 + srow[1]) * F + soff[1];
    const unsigned short* bSrc0 = Bt + (size_t)(n0 + srow[0]) * F + soff[0];
    const unsigned short* bSrc1 = Bt + (size_t)(n0 + srow[1]) * F + soff[1];

    const short* ap[4];
    const short* bp[4];
#pragma unroll
    for (int mb = 0; mb < 4; ++mb) {
        int m = wm0 + mb * 16 + lr;
        ap[mb] = &As[0][m * 32 + (q ^ ((m >> 1) & 3)) * 8];
        int n = wn0 + mb * 16 + lr;
        bp[mb] = &Bs[0][n * 32 + (q ^ ((n >> 1) & 3)) * 8];
    }

    floatx4 acc[4][4] = {};

    // prologue: stage tile 0 into buffer 0
    gl_lds16(aSrc0, &As[0][(wid)     * 512]);
    gl_lds16(aSrc1, &As[0][(wid + 4) * 512]);
    gl_lds16(bSrc0, &Bs[0][(wid)     * 512]);
    gl_lds16(bSrc1, &Bs[0][(wid + 4) * 512]);

    for (int kt = 0; kt < F / 32; ++kt) {
        const int buf = kt & 1;
        __syncthreads();                       // drains buf's loads (issued kt-1)
        if (kt + 1 < F / 32) {                 // prefetch next tile into other buf
            int k0 = (kt + 1) * 32;
            gl_lds16(aSrc0 + k0, &As[buf ^ 1][(wid)     * 512]);
            gl_lds16(aSrc1 + k0, &As[buf ^ 1][(wid + 4) * 512]);
            gl_lds16(bSrc0 + k0, &Bs[buf ^ 1][(wid)     * 512]);
            gl_lds16(bSrc1 + k0, &Bs[buf ^ 1][(wid + 4) * 512]);
        }
        const int bo = buf * (128 * 32);
        short8 af[4], bf[4];
#pragma unroll
        for (int mb = 0; mb < 4; ++mb) af[mb] = *(const short8*)(ap[mb] + bo);
#pragma unroll
        for (int nb = 0; nb < 4; ++nb) bf[nb] = *(const short8*)(bp[nb] + bo);
#pragma unroll
        for (int mb = 0; mb < 4; ++mb)
#pragma unroll
            for (int nb = 0; nb < 4; ++nb)
                acc[mb][nb] = __builtin_amdgcn_mfma_f32_16x16x32_bf16(
                    af[mb], bf[nb], acc[mb][nb], 0, 0, 0);
    }

    float s1[4][4], s2[4][4];
#pragma unroll
    for (int mb = 0; mb < 4; ++mb)
#pragma unroll
        for (int r = 0; r < 4; ++r) {
            int row = m0 + wm0 + mb * 16 + q * 4 + r;
            s1[mb][r] = rs1[row];
            s2[mb][r] = rs2[row];
        }
#pragma unroll
    for (int nb = 0; nb < 4; ++nb) {
        int col = n0 + wn0 + nb * 16 + lr;
        float bv = bias[col];
#pragma unroll
        for (int mb = 0; mb < 4; ++mb)
#pragma unroll
            for (int r = 0; r < 4; ++r) {
                int row = m0 + wm0 + mb * 16 + q * 4 + r;
                float v = fmaxf(acc[mb][nb][r] * s1[mb][r] + bv, 0.f) * s2[mb][r];
                Cb[(size_t)row * F + col] = f2bf(v);
            }
    }
}

// ---- bf16 MFMA GEMM, layer 3: z3 = x2' @ Wt3^T, fp32 out, N=64, dbuf ------
// BM=64, 4 waves (wave w -> rows w*16..w*16+15, cols 0..63), grid MPAD/64.
__global__ __launch_bounds__(256) void k_gemm3(
        const unsigned short* __restrict__ A,
        const unsigned short* __restrict__ Bt,   // [64 n][F k]
        float* __restrict__ Z) {
    __shared__ short As3[2][64 * 32];
    __shared__ short Bs3[2][64 * 32];
    const int t = threadIdx.x, lane = t & 63, wid = t >> 6;
    const int m0 = blockIdx.x * 64;
    const int lr = lane & 15, q = lane >> 4;

    const int r = wid * 16 + (lane >> 2);
    const int soff = (((lane & 3) ^ ((r >> 1) & 3)) * 8);
    const unsigned short* aSrc = A  + (size_t)(m0 + r) * F + soff;
    const unsigned short* bSrc = Bt + (size_t)r * F + soff;

    const short* ap;
    {
        int m = wid * 16 + lr;
        ap = &As3[0][m * 32 + (q ^ ((m >> 1) & 3)) * 8];
    }
    const short* bp[4];
#pragma unroll
    for (int nb = 0; nb < 4; ++nb) {
        int n = nb * 16 + lr;
        bp[nb] = &Bs3[0][n * 32 + (q ^ ((n >> 1) & 3)) * 8];
    }

    floatx4 acc[4] = {};

    gl_lds16(aSrc, &As3[0][wid * 512]);
    gl_lds16(bSrc, &Bs3[0][wid * 512]);

    for (int kt = 0; kt < F / 32; ++kt) {
        const int buf = kt & 1;
        __syncthreads();
        if (kt + 1 < F / 32) {
            int k0 = (kt + 1) * 32;
            gl_lds16(aSrc + k0, &As3[buf ^ 1][wid * 512]);
            gl_lds16(bSrc + k0, &Bs3[buf ^ 1][wid * 512]);
        }
        const int bo = buf * (64 * 32);
        short8 af = *(const short8*)(ap + bo);
        short8 bf[4];
#pragma unroll
        for (int nb = 0; nb < 4; ++nb) bf[nb] = *(const short8*)(bp[nb] + bo);
#pragma unroll
        for (int nb = 0; nb < 4; ++nb)
            acc[nb] = __builtin_amdgcn_mfma_f32_16x16x32_bf16(af, bf[nb], acc[nb], 0, 0, 0);
    }

#pragma unroll
    for (int nb = 0; nb < 4; ++nb) {
        int col = nb * 16 + lr;
#pragma unroll
        for (int ri = 0; ri < 4; ++ri) {
            int row = m0 + wid * 16 + q * 4 + ri;
            Z[(size_t)row * C3 + col] = acc[nb][ri];
        }
    }
}

// ---- driver ---------------------------------------------------------------

extern "C" void kernel_launch(void* const* d_in, const int* in_sizes, int n_in,
                              void* d_out, int out_size, void* d_ws, size_t ws_size,
                              hipStream_t stream) {
    const float* h   = (const float*)d_in[0];
    const int*   src = (const int*)d_in[1];
    const int*   dst = (const int*)d_in[2];
    const float* W1  = (const float*)d_in[3];
    const float* b1  = (const float*)d_in[4];
    const float* W2  = (const float*)d_in[5];
    const float* b2  = (const float*)d_in[6];
    const float* W3  = (const float*)d_in[7];
    const float* b3  = (const float*)d_in[8];
    float* out = (float*)d_out;

    char* ws = (char*)d_ws;
    int*   deg_out  = (int*)ws;                       ws += MPAD * 4;
    int*   deg_in   = (int*)ws;                       ws += MPAD * 4;
    float* norm_src = (float*)ws;                     ws += MPAD * 4;
    float* norm_dst = (float*)ws;                     ws += MPAD * 4;
    int*   row_ptr  = (int*)ws;                       ws += (NN + 1) * 4;
    int*   cursor   = (int*)ws;                       ws += NN * 4;
    int*   csr_src  = (int*)ws;                       ws += NE * 4;
    ws = (char*)(((size_t)ws + 255) & ~(size_t)255);
    unsigned short* hb   = (unsigned short*)ws;       ws += (size_t)MPAD * F * 2;
    unsigned short* aggb = (unsigned short*)ws;       ws += (size_t)MPAD * F * 2;
    unsigned short* xb   = (unsigned short*)ws;       ws += (size_t)MPAD * F * 2;
    unsigned short* Wt1  = (unsigned short*)ws;       ws += (size_t)F * F * 2;
    unsigned short* Wt2  = (unsigned short*)ws;       ws += (size_t)F * F * 2;
    unsigned short* Wt3  = (unsigned short*)ws;       ws += (size_t)C3 * F * 2;
    float* z3       = (float*)ws;                     // MPAD * C3 * 4

    // CSR build + norms + weight conversion + h conversion
    hipMemsetAsync(deg_out, 0, 2 * MPAD * sizeof(int), stream);
    k_degree<<<(NE + 255) / 256, 256, 0, stream>>>(src, dst, deg_out, deg_in);
    k_norm<<<(MPAD + 255) / 256, 256, 0, stream>>>(deg_out, deg_in, norm_src, norm_dst);
    k_scan<<<1, 1024, 0, stream>>>(deg_in, row_ptr, cursor);
    k_bucket<<<(NE + 255) / 256, 256, 0, stream>>>(src, dst, cursor, csr_src);
    k_wconv<<<dim3(F / 32, F / 32), 256, 0, stream>>>(W1, Wt1, F);
    k_wconv<<<dim3(F / 32, F / 32), 256, 0, stream>>>(W2, Wt2, F);
    k_wconv<<<dim3(C3 / 32, F / 32), 256, 0, stream>>>(W3, Wt3, C3);
    k_hcvt<<<NN * 128 / 256, 256, 0, stream>>>(h, norm_src, hb);

    // layer 1: aggb = Sum hb[src]; xb = bf16(ns.*relu(nd.*(aggb@W1)+b1))
    k_aggb<<<(NN / 16) * 8, 256, 0, stream>>>(hb, row_ptr, csr_src, aggb);
    k_gemm_bf16<<<(MPAD / 128) * (F / 128), 256, 0, stream>>>(aggb, Wt1, b1, norm_dst, norm_src, xb);

    // layer 2
    k_aggb<<<(NN / 16) * 8, 256, 0, stream>>>(xb, row_ptr, csr_src, aggb);
    k_gemm_bf16<<<(MPAD / 128) * (F / 128), 256, 0, stream>>>(aggb, Wt2, b2, norm_dst, norm_src, xb);

    // layer 3: z3 = xb @ W3t ; out = nd.*(A z3) + b3
    k_gemm3<<<MPAD / 64, 256, 0, stream>>>(xb, Wt3, z3);
    k_agg64<<<(NN + 15) / 16, 256, 0, stream>>>(z3, row_ptr, csr_src, norm_dst, b3, out);
}